// Round 12
// baseline (321.797 us; speedup 1.0000x reference)
//
#include <hip/hip_runtime.h>
#include <math.h>

#define LDIM 256
#define NCODES 1024
#define HID 256
#define NLAY 5
#define NVQ 4
#define CC_ 0.25f
#define OMEGA_ 30.0f
#define BATCH 16
#define NPTS 4096
#define PTILE 64    // points per siren block (74 KB LDS -> 2 blocks/CU)

// ws layout (bytes):
//   [0      .. 16383 ] z per batch (16x256 f32)
//   [16384  .. 16895 ] winners: 16 batches x 4 stages u64 (low 32 = idx)
//   [32768  .. 163839] FiLM params
//   fast path (ws_size >= 1,245,184 -- PROVEN: r10/r11 fast path executed):
//   [196608 .. 720895 ] wpf_hi: bf16 hi plane, fragment-linear [li][htile16][kc8][lane64][8]
//   [720896 .. 1245183] wpf_lo: bf16 lo plane, same order
#define WIN_OFF 4096
#define FILM_OFF 8192
#define WP_BYTE 196608
#define PLANE_SHORTS (4 * 16 * 8 * 64 * 8)
#define FAST_WS_NEEDED 1245184u

typedef __attribute__((ext_vector_type(8))) short short8;
typedef __attribute__((ext_vector_type(4))) float f32x4;

__device__ __forceinline__ unsigned int pack_split(float x) {
  unsigned int u = __builtin_bit_cast(unsigned int, x);
  float hf = __builtin_bit_cast(float, u & 0xffff0000u);
  float lf = x - hf;
  unsigned int ul = __builtin_bit_cast(unsigned int, lf);
  return (u & 0xffff0000u) | (ul >> 16);
}
__device__ __forceinline__ void split_trunc(float x, short& hi, short& lo) {
  unsigned int u = __builtin_bit_cast(unsigned int, x);
  float hf = __builtin_bit_cast(float, u & 0xffff0000u);
  float lf = x - hf;
  hi = (short)(u >> 16);
  lo = (short)(__builtin_bit_cast(unsigned int, lf) >> 16);
}
__device__ __forceinline__ float bf16_hi_f(unsigned short h) {
  return __builtin_bit_cast(float, (unsigned int)h << 16);
}

// ---------------- vq_all: all 4 residual-VQ stages in ONE launch ----------------
// 16 blocks (one per batch) x 512 threads. 64-code LDS chunks; wave wv handles
// codes c_local = wv*8 + (lane>>3); exact first-index tie-break (ordered chunk
// scan with strict <, then lexicographic (val,idx) tree reduce).
__global__ __launch_bounds__(512) void vq_all(const int* __restrict__ lidx,
                                              const float* __restrict__ latents,
                                              const float* __restrict__ emb,
                                              float* __restrict__ ws) {
  __shared__ __align__(16) float Ech[64 * 260];  // 66,560 B
  __shared__ __align__(16) float r_s[LDIM];
  __shared__ float mval[64];
  __shared__ int   midx[64];
  const int t = threadIdx.x;
  const int b = blockIdx.x;
  const int lane = t & 63;
  const int wv = t >> 6;
  const int cg = lane >> 3;      // code slot 0..7 within wave
  const int dq = lane & 7;       // dim octant
  const int c_local = wv * 8 + cg;

  if (t < LDIM) {
    const int ib = lidx[b];
    float z = 0.f;
    #pragma unroll
    for (int v = 0; v < NVQ; ++v) z += latents[((size_t)ib * NVQ + v) * LDIM + t];
    ws[b * LDIM + t] = z;
    r_s[t] = z;
  }
  __syncthreads();

  for (int s = 0; s < NVQ; ++s) {
    const float* E = emb + (size_t)s * NCODES * LDIM;
    const float4* E4 = (const float4*)E;
    float bestv = 3.4e38f; int besti = 0;
    for (int ch = 0; ch < 16; ++ch) {       // 16 chunks of 64 codes
      __syncthreads();   // also protects r_s update from prev stage / Ech reuse
      #pragma unroll
      for (int it = 0; it < 8; ++it) {      // stage 64x256 floats, coalesced
        int f = it * 512 + t;
        int row = f >> 6;
        int col4 = f & 63;
        *(float4*)&Ech[row * 260 + col4 * 4] = E4[(size_t)(ch * 64 + row) * 64 + col4];
      }
      __syncthreads();
      const float* er = &Ech[c_local * 260];
      const float4* rr4 = (const float4*)r_s;
      float dot = 0.f, e2 = 0.f;
      #pragma unroll
      for (int j = 0; j < 8; ++j) {
        int d4 = dq + 8 * j;
        float4 e = *(const float4*)&er[d4 * 4];
        float4 rv = rr4[d4];
        dot += e.x * rv.x + e.y * rv.y + e.z * rv.z + e.w * rv.w;
        e2  += e.x * e.x + e.y * e.y + e.z * e.z + e.w * e.w;
      }
      dot += __shfl_xor(dot, 1); e2 += __shfl_xor(e2, 1);
      dot += __shfl_xor(dot, 2); e2 += __shfl_xor(e2, 2);
      dot += __shfl_xor(dot, 4); e2 += __shfl_xor(e2, 4);
      if (dq == 0) {
        float dist = e2 - 2.f * dot;        // +||r||^2 constant: argmin-invariant
        int c = ch * 64 + c_local;
        if (dist < bestv) { bestv = dist; besti = c; }  // strict <: earliest chunk wins
      }
    }
    __syncthreads();
    if (dq == 0) { mval[c_local] = bestv; midx[c_local] = besti; }
    __syncthreads();
    for (int off = 32; off > 0; off >>= 1) {
      if (t < off) {
        float ov = mval[t + off]; int oi = midx[t + off];
        if (ov < mval[t] || (ov == mval[t] && oi < midx[t])) { mval[t] = ov; midx[t] = oi; }
      }
      __syncthreads();
    }
    const int best = midx[0];
    if (t < LDIM) r_s[t] -= E[(size_t)best * LDIM + t];
    if (t == 0)
      ((unsigned long long*)(ws + WIN_OFF))[b * NVQ + s] = (unsigned long long)(unsigned int)best;
    __syncthreads();
  }
}

// ---------------- FiLM params + loss (grid 65) ----------------
__global__ __launch_bounds__(256) void film_loss(const float* __restrict__ emb,
                                                 const float* __restrict__ mod_W,
                                                 const float* __restrict__ mod_b,
                                                 float* __restrict__ ws,
                                                 float* __restrict__ loss_out) {
  __shared__ float z_s[LDIM];
  const int t = threadIdx.x;
  const unsigned long long* wsl = (const unsigned long long*)(ws + WIN_OFF);
  if (blockIdx.x == 64) {
    __shared__ float red[256];
    float acc = 0.f;
    for (int b = 0; b < BATCH; ++b) {
      float r = ws[b * LDIM + t];
      #pragma unroll
      for (int s = 0; s < NVQ; ++s) {
        int w = (int)(wsl[b * NVQ + s] & 0xffffffffULL);
        float e = emb[((size_t)s * NCODES + w) * LDIM + t];
        float d = e - r;
        acc += d * d;
        r -= e;
      }
    }
    red[t] = acc;
    __syncthreads();
    for (int off = 128; off > 0; off >>= 1) {
      if (t < off) red[t] += red[t + off];
      __syncthreads();
    }
    if (t == 0) loss_out[0] = red[0] * (CC_ / (NVQ * BATCH * LDIM));
    return;
  }
  const int li = blockIdx.x & 3;
  const int b  = blockIdx.x >> 2;
  const int l  = li + 1;
  float z = 0.f;
  #pragma unroll
  for (int s = 0; s < NVQ; ++s) {
    int w = (int)(wsl[b * NVQ + s] & 0xffffffffULL);
    z += emb[((size_t)s * NCODES + w) * LDIM + t];
  }
  z_s[t] = z;
  __syncthreads();
  float m1 = mod_b[l * 2 * HID + t];
  float m2 = mod_b[l * 2 * HID + HID + t];
  const float* Wm = mod_W + (size_t)l * LDIM * 2 * HID;
  #pragma unroll 4
  for (int d = 0; d < LDIM; ++d) {
    float zd = z_s[d];
    m1 = fmaf(zd, Wm[d * 2 * HID + t], m1);
    m2 = fmaf(zd, Wm[d * 2 * HID + HID + t], m2);
  }
  float* film = ws + FILM_OFF;
  film[((b * 4 + li) * 2 + 0) * HID + t] = 1.f + m1;
  film[((b * 4 + li) * 2 + 1) * HID + t] = m2;
}

// ---------------- prep_w (unchanged layout; htile covers both wave tilings) ----------------
__global__ __launch_bounds__(256) void prep_w(const float* __restrict__ Whg,
                                              float* __restrict__ ws) {
  const int li = blockIdx.x >> 3;
  const int c  = blockIdx.x & 7;
  const int t = threadIdx.x;
  const int lane = t & 63;
  const int n = lane & 15, q = lane >> 4;
  short* wp_hi = (short*)((char*)ws + WP_BYTE);
  short* wp_lo = wp_hi + PLANE_SHORTS;
  for (int h_t = (t >> 6); h_t < 16; h_t += 4) {
    short8 hv, lv;
    #pragma unroll
    for (int j = 0; j < 8; ++j) {
      float x = Whg[((size_t)(li * 256 + c * 32 + q * 8 + j)) * 256 + h_t * 16 + n];
      short hi, lo;
      split_trunc(x, hi, lo);
      hv[j] = hi; lv[j] = lo;
    }
    size_t off = ((((size_t)li * 16 + h_t) * 8 + c) * 64 + lane) * 8;
    *(short8*)&wp_hi[off] = hv;
    *(short8*)&wp_lo[off] = lv;
  }
}

// ---------------- FAST siren: PTILE=64, 74 KB LDS -> 2 blocks/CU ----------------
// Wave tile 64p x 32h (hq=wv, htile=hq*2+ht): no B duplication across waves.
__global__ __launch_bounds__(512) void siren_mfma_fast(
    const float* __restrict__ coords,
    const float* __restrict__ W0,
    const float* __restrict__ b0,
    const float* __restrict__ bhv,
    const float* __restrict__ Wl,
    const float* __restrict__ bl,
    const float* __restrict__ ws,
    float* __restrict__ out) {
  __shared__ short x_h[PTILE * 264];   // 33,792 B
  __shared__ short x_l[PTILE * 264];   // 33,792 B
  __shared__ float osum[PTILE * 8 * 3];// 6,144 B
  const int tid = threadIdx.x;
  const int bp = blockIdx.x;
  const int b = bp >> 6;               // 64 tiles per batch
  const int tile = bp & 63;
  const int pbase = b * NPTS + tile * PTILE;

  // ---- layer 0 ----
  {
    const int oct = tid >> 6;          // 8 octants of 32 dims
    const int p = tid & 63;
    const float c0 = coords[(size_t)(pbase + p) * 2 + 0];
    const float c1 = coords[(size_t)(pbase + p) * 2 + 1];
    const int d0 = oct * 32;
    for (int i = 0; i < 32; i += 8) {
      short8 hv, lv;
      #pragma unroll
      for (int j = 0; j < 8; ++j) {
        int d = d0 + i + j;
        float pre = fmaf(c0, W0[d], fmaf(c1, W0[HID + d], b0[d]));
        short hi, lo;
        split_trunc(__sinf(OMEGA_ * pre), hi, lo);
        hv[j] = hi; lv[j] = lo;
      }
      *(short8*)&x_h[p * 264 + d0 + i] = hv;
      *(short8*)&x_l[p * 264 + d0 + i] = lv;
    }
  }

  const int lane = tid & 63;
  const int hq = tid >> 6;       // wave 0..7 -> 32-h strip
  const int hb = hq * 32;
  const int n = lane & 15;
  const int q = lane >> 4;

  const short* wp_hi = (const short*)((const char*)ws + WP_BYTE);
  const short* wp_lo = wp_hi + PLANE_SHORTS;
  const float* film = ws + FILM_OFF;

  for (int layer = 1; layer < NLAY; ++layer) {
    const int li = layer - 1;
    f32x4 acc[4][2];
    #pragma unroll
    for (int pt = 0; pt < 4; ++pt)
      #pragma unroll
      for (int ht = 0; ht < 2; ++ht)
        acc[pt][ht] = (f32x4){0.f, 0.f, 0.f, 0.f};

    __syncthreads();

    #pragma unroll 2
    for (int kc = 0; kc < HID; kc += 32) {
      const int c = kc >> 5;
      short8 Bh[2], Bl[2];
      #pragma unroll
      for (int ht = 0; ht < 2; ++ht) {
        const size_t wb = ((((size_t)li * 16 + hq * 2 + ht) * 8 + c) * 64 + lane) * 8;
        Bh[ht] = *(const short8*)&wp_hi[wb];
        Bl[ht] = *(const short8*)&wp_lo[wb];
      }
      short8 Ah[4], Al[4];
      #pragma unroll
      for (int pt = 0; pt < 4; ++pt) {
        const int xb = (pt * 16 + n) * 264 + kc + q * 8;
        Ah[pt] = *(const short8*)&x_h[xb];
        Al[pt] = *(const short8*)&x_l[xb];
      }
      #pragma unroll
      for (int ht = 0; ht < 2; ++ht)
        #pragma unroll
        for (int pt = 0; pt < 4; ++pt)
          acc[pt][ht] = __builtin_amdgcn_mfma_f32_16x16x32_bf16(Ah[pt], Bh[ht], acc[pt][ht], 0, 0, 0);
      #pragma unroll
      for (int ht = 0; ht < 2; ++ht)
        #pragma unroll
        for (int pt = 0; pt < 4; ++pt)
          acc[pt][ht] = __builtin_amdgcn_mfma_f32_16x16x32_bf16(Ah[pt], Bl[ht], acc[pt][ht], 0, 0, 0);
      #pragma unroll
      for (int ht = 0; ht < 2; ++ht)
        #pragma unroll
        for (int pt = 0; pt < 4; ++pt)
          acc[pt][ht] = __builtin_amdgcn_mfma_f32_16x16x32_bf16(Al[pt], Bh[ht], acc[pt][ht], 0, 0, 0);
    }

    __syncthreads();

    // epilogue: D layout col(h)=lane&15, row(p)=q*4+r
    #pragma unroll
    for (int ht = 0; ht < 2; ++ht) {
      const int h = hb + ht * 16 + n;
      const float bias = bhv[li * HID + h];
      const float g1 = film[((b * 4 + li) * 2 + 0) * HID + h];
      const float bt = film[((b * 4 + li) * 2 + 1) * HID + h];
      #pragma unroll
      for (int pt = 0; pt < 4; ++pt) {
        #pragma unroll
        for (int r = 0; r < 4; ++r) {
          float pre = acc[pt][ht][r] + bias;
          pre = fmaf(pre, g1, bt);
          short hi, lo;
          split_trunc(__sinf(OMEGA_ * pre), hi, lo);
          const int row = pt * 16 + q * 4 + r;
          x_h[row * 264 + h] = hi;
          x_l[row * 264 + h] = lo;
        }
      }
    }
  }
  __syncthreads();

  // ---- output layer ----
  {
    const int p = tid >> 3;        // 64 points
    const int dq = tid & 7;        // 8 chunks of 32 dims
    float v0 = 0.f, v1 = 0.f, v2 = 0.f;
    for (int i = 0; i < 32; ++i) {
      int d = dq * 32 + i;
      float xv = bf16_hi_f((unsigned short)x_h[p * 264 + d]) +
                 bf16_hi_f((unsigned short)x_l[p * 264 + d]);
      v0 = fmaf(xv, Wl[d * 3 + 0], v0);
      v1 = fmaf(xv, Wl[d * 3 + 1], v1);
      v2 = fmaf(xv, Wl[d * 3 + 2], v2);
    }
    osum[(p * 8 + dq) * 3 + 0] = v0;
    osum[(p * 8 + dq) * 3 + 1] = v1;
    osum[(p * 8 + dq) * 3 + 2] = v2;
  }
  __syncthreads();
  if (tid < PTILE) {
    const int p = tid;
    float v[3] = {bl[0], bl[1], bl[2]};
    #pragma unroll
    for (int dq = 0; dq < 8; ++dq)
      #pragma unroll
      for (int c = 0; c < 3; ++c) v[c] += osum[(p * 8 + dq) * 3 + c];
    size_t o = (size_t)(pbase + p) * 3;
    out[o + 0] = v[0]; out[o + 1] = v[1]; out[o + 2] = v[2];
  }
}

// ---------------- FALLBACK siren (round-8-proven; PTILE=128; dead when ws large) ----------------
__global__ __launch_bounds__(512) void siren_mfma(
    const float* __restrict__ coords,
    const float* __restrict__ W0,
    const float* __restrict__ b0,
    const float* __restrict__ Whg,
    const float* __restrict__ bhv,
    const float* __restrict__ Wl,
    const float* __restrict__ bl,
    const float* __restrict__ ws,
    float* __restrict__ out) {
  __shared__ unsigned int x_u[128 * 260];
  __shared__ float osum[128 * 4 * 3];
  const int tid = threadIdx.x;
  const int bp = blockIdx.x;
  const int b = bp >> 5;
  const int tile = bp & 31;
  const int pbase = b * NPTS + tile * 128;
  {
    const int quarter = tid >> 7;
    const int p = tid & 127;
    const float c0 = coords[(size_t)(pbase + p) * 2 + 0];
    const float c1 = coords[(size_t)(pbase + p) * 2 + 1];
    const int d0 = quarter * 64;
    for (int i = 0; i < 64; i += 4) {
      unsigned int buf[4];
      #pragma unroll
      for (int j = 0; j < 4; ++j) {
        int d = d0 + i + j;
        float pre = fmaf(c0, W0[d], fmaf(c1, W0[HID + d], b0[d]));
        buf[j] = pack_split(__sinf(OMEGA_ * pre));
      }
      *(uint4*)&x_u[p * 260 + d0 + i] = *(uint4*)buf;
    }
  }
  const int lane = tid & 63;
  const int wv = tid >> 6;
  const int pg = wv & 1;
  const int hq = wv >> 1;
  const int pb = pg * 64;
  const int hb = hq * 64;
  const int n = lane & 15;
  const int q = lane >> 4;
  const float* film = ws + FILM_OFF;
  for (int layer = 1; layer < NLAY; ++layer) {
    const int li = layer - 1;
    f32x4 acc[4][4];
    #pragma unroll
    for (int pt = 0; pt < 4; ++pt)
      #pragma unroll
      for (int ht = 0; ht < 4; ++ht)
        acc[pt][ht] = (f32x4){0.f, 0.f, 0.f, 0.f};
    __syncthreads();
    for (int kc = 0; kc < HID; kc += 32) {
      short8 Bh[4], Bl[4];
      #pragma unroll
      for (int ht = 0; ht < 4; ++ht) {
        const float* wbase = Whg + ((size_t)(li * 256 + kc + q * 8)) * 256 + hb + ht * 16 + n;
        #pragma unroll
        for (int j = 0; j < 8; ++j) {
          short hi, lo;
          split_trunc(wbase[(size_t)j * 256], hi, lo);
          Bh[ht][j] = hi; Bl[ht][j] = lo;
        }
      }
      short8 ah[4], al[4];
      #pragma unroll
      for (int pt = 0; pt < 4; ++pt) {
        const uint4* ap = (const uint4*)&x_u[(pb + pt * 16 + n) * 260 + kc + q * 8];
        uint4 a0 = ap[0], a1 = ap[1];
        unsigned int aw[8] = {a0.x, a0.y, a0.z, a0.w, a1.x, a1.y, a1.z, a1.w};
        #pragma unroll
        for (int j = 0; j < 8; ++j) {
          ah[pt][j] = (short)(aw[j] >> 16);
          al[pt][j] = (short)(aw[j] & 0xffffu);
        }
      }
      #pragma unroll
      for (int ht = 0; ht < 4; ++ht)
        #pragma unroll
        for (int pt = 0; pt < 4; ++pt)
          acc[pt][ht] = __builtin_amdgcn_mfma_f32_16x16x32_bf16(ah[pt], Bh[ht], acc[pt][ht], 0, 0, 0);
      #pragma unroll
      for (int ht = 0; ht < 4; ++ht)
        #pragma unroll
        for (int pt = 0; pt < 4; ++pt)
          acc[pt][ht] = __builtin_amdgcn_mfma_f32_16x16x32_bf16(ah[pt], Bl[ht], acc[pt][ht], 0, 0, 0);
      #pragma unroll
      for (int ht = 0; ht < 4; ++ht)
        #pragma unroll
        for (int pt = 0; pt < 4; ++pt)
          acc[pt][ht] = __builtin_amdgcn_mfma_f32_16x16x32_bf16(al[pt], Bh[ht], acc[pt][ht], 0, 0, 0);
    }
    __syncthreads();
    #pragma unroll
    for (int ht = 0; ht < 4; ++ht) {
      const int h = hb + ht * 16 + n;
      const float bias = bhv[li * HID + h];
      const float g1 = film[((b * 4 + li) * 2 + 0) * HID + h];
      const float bt = film[((b * 4 + li) * 2 + 1) * HID + h];
      #pragma unroll
      for (int pt = 0; pt < 4; ++pt) {
        #pragma unroll
        for (int r = 0; r < 4; ++r) {
          float pre = acc[pt][ht][r] + bias;
          pre = fmaf(pre, g1, bt);
          x_u[(pb + pt * 16 + q * 4 + r) * 260 + h] = pack_split(__sinf(OMEGA_ * pre));
        }
      }
    }
  }
  __syncthreads();
  {
    const int p = tid >> 2;
    const int dq = tid & 3;
    float v0 = 0.f, v1 = 0.f, v2 = 0.f;
    for (int i = 0; i < 64; ++i) {
      int d = dq * 64 + i;
      unsigned int wrd = x_u[p * 260 + d];
      float xv = bf16_hi_f((unsigned short)(wrd >> 16)) +
                 bf16_hi_f((unsigned short)(wrd & 0xffffu));
      v0 = fmaf(xv, Wl[d * 3 + 0], v0);
      v1 = fmaf(xv, Wl[d * 3 + 1], v1);
      v2 = fmaf(xv, Wl[d * 3 + 2], v2);
    }
    osum[(p * 4 + dq) * 3 + 0] = v0;
    osum[(p * 4 + dq) * 3 + 1] = v1;
    osum[(p * 4 + dq) * 3 + 2] = v2;
  }
  __syncthreads();
  if (tid < 128) {
    const int p = tid;
    float v[3] = {bl[0], bl[1], bl[2]};
    #pragma unroll
    for (int dq = 0; dq < 4; ++dq)
      #pragma unroll
      for (int c = 0; c < 3; ++c) v[c] += osum[(p * 4 + dq) * 3 + c];
    size_t o = (size_t)(pbase + p) * 3;
    out[o + 0] = v[0]; out[o + 1] = v[1]; out[o + 2] = v[2];
  }
}

extern "C" void kernel_launch(void* const* d_in, const int* in_sizes, int n_in,
                              void* d_out, int out_size, void* d_ws, size_t ws_size,
                              hipStream_t stream) {
  (void)in_sizes; (void)n_in;
  const float* coords  = (const float*)d_in[0];
  const int*   lidx    = (const int*)d_in[1];
  const float* latents = (const float*)d_in[2];
  const float* emb     = (const float*)d_in[3];
  const float* mod_W   = (const float*)d_in[4];
  const float* mod_b   = (const float*)d_in[5];
  const float* W0      = (const float*)d_in[6];
  const float* b0      = (const float*)d_in[7];
  const float* Wh      = (const float*)d_in[8];
  const float* bh      = (const float*)d_in[9];
  const float* Wl      = (const float*)d_in[10];
  const float* bl      = (const float*)d_in[11];
  float* out = (float*)d_out;
  float* ws  = (float*)d_ws;
  float* loss_out = out + (out_size - 1);

  const bool fast = (ws_size >= FAST_WS_NEEDED);
  if (fast) prep_w<<<32, 256, 0, stream>>>(Wh, ws);
  vq_all<<<BATCH, 512, 0, stream>>>(lidx, latents, emb, ws);
  film_loss<<<BATCH * 4 + 1, 256, 0, stream>>>(emb, mod_W, mod_b, ws, loss_out);
  if (fast)
    siren_mfma_fast<<<(BATCH * NPTS) / PTILE, 512, 0, stream>>>(coords, W0, b0, bh, Wl, bl, ws, out);
  else
    siren_mfma<<<(BATCH * NPTS) / 128, 512, 0, stream>>>(coords, W0, b0, Wh, bh, Wl, bl, ws, out);
}

// Round 13
// 278.419 us; speedup vs baseline: 1.1558x; 1.1558x over previous
//
#include <hip/hip_runtime.h>
#include <math.h>

#define LDIM 256
#define NCODES 1024
#define HID 256
#define NLAY 5
#define NVQ 4
#define CC_ 0.25f
#define OMEGA_ 30.0f
#define BATCH 16
#define NPTS 4096
#define PTILE 64    // siren points/block (74 KB LDS -> 2 blocks/CU, r12-proven)

// ws layout (float indices):
//   [0    .. 4095] z per batch (16x256)
//   [4096 .. 4223] winners u64[16][4] (low 32 = idx)
//   [4224 .. 5247] VQ stage partials u64[16][4][8]
//   [5280 .. 5287] barrier counters u32[8] (stages 0..3)
//   [5288]         init flag u32
//   [8192 .. 40959] FiLM params
//   fast path (ws_size >= 1,245,184 -- PROVEN r10-r12):
//   bytes [196608..720895] wpf_hi, [720896..1245183] wpf_lo (fragment-linear)
#define WIN_OFF 4096
#define PART_OFF 4224
#define CNT_OFF 5280
#define FLAG_OFF 5288
#define FILM_OFF 8192
#define WP_BYTE 196608
#define PLANE_SHORTS (4 * 16 * 8 * 64 * 8)
#define FAST_WS_NEEDED 1245184u
#define MAGIC_ 0x13572468u

typedef __attribute__((ext_vector_type(8))) short short8;
typedef __attribute__((ext_vector_type(4))) float f32x4;

__device__ __forceinline__ unsigned int pack_split(float x) {
  unsigned int u = __builtin_bit_cast(unsigned int, x);
  float hf = __builtin_bit_cast(float, u & 0xffff0000u);
  float lf = x - hf;
  unsigned int ul = __builtin_bit_cast(unsigned int, lf);
  return (u & 0xffff0000u) | (ul >> 16);
}
__device__ __forceinline__ void split_trunc(float x, short& hi, short& lo) {
  unsigned int u = __builtin_bit_cast(unsigned int, x);
  float hf = __builtin_bit_cast(float, u & 0xffff0000u);
  float lf = x - hf;
  hi = (short)(u >> 16);
  lo = (short)(__builtin_bit_cast(unsigned int, lf) >> 16);
}
__device__ __forceinline__ float bf16_hi_f(unsigned short h) {
  return __builtin_bit_cast(float, (unsigned int)h << 16);
}
__device__ __forceinline__ unsigned int mono_u32(float f) {
  unsigned int u = __builtin_bit_cast(unsigned int, f);
  return (u & 0x80000000u) ? ~u : (u | 0x80000000u);
}

// ---------------- vq_prep_fused: prep_w (blocks 0..31) + full residual VQ
// (blocks 32..159 = 16 batches x 8 slices) with device-scope stage barriers.
// All 160 blocks co-resident (<= 256 CUs) -> spin barriers safe; guarded anyway.
__global__ __launch_bounds__(256) void vq_prep_fused(
    const int* __restrict__ lidx,
    const float* __restrict__ latents,
    const float* __restrict__ emb,
    const float* __restrict__ Whg,
    float* __restrict__ ws, int do_prep) {
  const int blk = blockIdx.x;
  const int t = threadIdx.x;

  if (blk < 32) {   // ---- prep_w duty ----
    if (!do_prep) return;
    const int li = blk >> 3;
    const int c  = blk & 7;
    const int lane = t & 63;
    const int n = lane & 15, q = lane >> 4;
    short* wp_hi = (short*)((char*)ws + WP_BYTE);
    short* wp_lo = wp_hi + PLANE_SHORTS;
    for (int h_t = (t >> 6); h_t < 16; h_t += 4) {
      short8 hv, lv;
      #pragma unroll
      for (int j = 0; j < 8; ++j) {
        float x = Whg[((size_t)(li * 256 + c * 32 + q * 8 + j)) * 256 + h_t * 16 + n];
        short hi, lo;
        split_trunc(x, hi, lo);
        hv[j] = hi; lv[j] = lo;
      }
      size_t off = ((((size_t)li * 16 + h_t) * 8 + c) * 64 + lane) * 8;
      *(short8*)&wp_hi[off] = hv;
      *(short8*)&wp_lo[off] = lv;
    }
    return;
  }

  // ---- VQ duty ----
  __shared__ __align__(16) float Ech[32 * 260];
  __shared__ __align__(16) float r_s[LDIM];
  __shared__ float mval[256];
  __shared__ int   midx[256];
  __shared__ int   bcast;
  const int vqb = blk - 32;
  const int b = vqb >> 3;
  const int slice = vqb & 7;
  unsigned int* cnt  = (unsigned int*)(ws + CNT_OFF);
  unsigned int* flag = (unsigned int*)(ws + FLAG_OFF);
  unsigned long long* part = (unsigned long long*)(ws + PART_OFF);
  unsigned long long* winners = (unsigned long long*)(ws + WIN_OFF);

  if (vqb == 0 && t == 0) {   // init duty: zero counters, then publish flag
    #pragma unroll
    for (int i = 0; i < 8; ++i)
      __hip_atomic_store(&cnt[i], 0u, __ATOMIC_RELAXED, __HIP_MEMORY_SCOPE_AGENT);
    __hip_atomic_store(flag, MAGIC_, __ATOMIC_RELEASE, __HIP_MEMORY_SCOPE_AGENT);
  }

  const int ib = lidx[b];
  float z = 0.f;
  #pragma unroll
  for (int v = 0; v < NVQ; ++v) z += latents[((size_t)ib * NVQ + v) * LDIM + t];
  r_s[t] = z;
  if (slice == 0) ws[b * LDIM + t] = z;   // film_loss reads z next launch

  if (t == 0) {   // wait for counter init (0xAA poison -> MAGIC)
    int guard = 0;
    while (__hip_atomic_load(flag, __ATOMIC_ACQUIRE, __HIP_MEMORY_SCOPE_AGENT) != MAGIC_
           && guard < (1 << 21)) { __builtin_amdgcn_s_sleep(8); ++guard; }
  }
  __syncthreads();

  const int cg = t >> 3;   // code 0..31 in chunk
  const int dq = t & 7;    // dim octant

  for (int s = 0; s < NVQ; ++s) {
    const float* E = emb + (size_t)s * NCODES * LDIM + (size_t)slice * 128 * LDIM;
    const float4* E4 = (const float4*)E;
    float bestv = 3.4e38f; int besti = 0;
    for (int ch = 0; ch < 4; ++ch) {
      __syncthreads();
      #pragma unroll
      for (int it = 0; it < 8; ++it) {
        int f = it * 256 + t;
        int row = f >> 6;
        int col4 = f & 63;
        *(float4*)&Ech[row * 260 + col4 * 4] = E4[(size_t)(ch * 32 + row) * 64 + col4];
      }
      __syncthreads();
      float dot = 0.f, e2 = 0.f;
      const float* er = &Ech[cg * 260];
      const float4* rr4 = (const float4*)r_s;
      #pragma unroll
      for (int j = 0; j < 8; ++j) {
        int d4 = dq + 8 * j;
        float4 e = *(const float4*)&er[d4 * 4];
        float4 rv = rr4[d4];
        dot += e.x * rv.x + e.y * rv.y + e.z * rv.z + e.w * rv.w;
        e2  += e.x * e.x + e.y * e.y + e.z * e.z + e.w * e.w;
      }
      dot += __shfl_xor(dot, 1); e2 += __shfl_xor(e2, 1);
      dot += __shfl_xor(dot, 2); e2 += __shfl_xor(e2, 2);
      dot += __shfl_xor(dot, 4); e2 += __shfl_xor(e2, 4);
      if (dq == 0) {
        float dist = e2 - 2.f * dot;   // +||r||^2 constant: argmin-invariant
        int c = slice * 128 + ch * 32 + cg;
        if (dist < bestv) { bestv = dist; besti = c; }
      }
    }
    mval[t] = (dq == 0) ? bestv : 3.4e38f;
    midx[t] = (dq == 0) ? besti : (1 << 30);
    __syncthreads();
    for (int off = 128; off > 0; off >>= 1) {
      if (t < off) {
        float ov = mval[t + off]; int oi = midx[t + off];
        if (ov < mval[t] || (ov == mval[t] && oi < midx[t])) { mval[t] = ov; midx[t] = oi; }
      }
      __syncthreads();
    }
    if (t == 0) {
      unsigned long long pack =
          ((unsigned long long)mono_u32(mval[0]) << 32) | (unsigned int)midx[0];
      __hip_atomic_store(&part[(b * NVQ + s) * 8 + slice], pack,
                         __ATOMIC_RELAXED, __HIP_MEMORY_SCOPE_AGENT);
      __hip_atomic_fetch_add(&cnt[s], 1u, __ATOMIC_RELEASE, __HIP_MEMORY_SCOPE_AGENT);
      int guard = 0;   // arrive-and-spin: all 128 VQ blocks per stage
      while (__hip_atomic_load(&cnt[s], __ATOMIC_ACQUIRE, __HIP_MEMORY_SCOPE_AGENT) < 128u
             && guard < (1 << 21)) { __builtin_amdgcn_s_sleep(8); ++guard; }
      unsigned long long best =
          __hip_atomic_load(&part[(b * NVQ + s) * 8 + 0], __ATOMIC_RELAXED, __HIP_MEMORY_SCOPE_AGENT);
      #pragma unroll
      for (int s2 = 1; s2 < 8; ++s2) {
        unsigned long long v =
            __hip_atomic_load(&part[(b * NVQ + s) * 8 + s2], __ATOMIC_RELAXED, __HIP_MEMORY_SCOPE_AGENT);
        if (v < best) best = v;   // u64 min == lexicographic (dist, first idx)
      }
      bcast = (int)(best & 0xffffffffULL);
      if (slice == 0) winners[b * NVQ + s] = (unsigned long long)(unsigned int)bcast;
    }
    __syncthreads();
    const int w = bcast;
    r_s[t] -= emb[((size_t)s * NCODES + w) * LDIM + t];
    __syncthreads();
  }
}

// ---------------- FiLM params + loss (grid 65) — unchanged (r10-r12 proven) ----------------
__global__ __launch_bounds__(256) void film_loss(const float* __restrict__ emb,
                                                 const float* __restrict__ mod_W,
                                                 const float* __restrict__ mod_b,
                                                 float* __restrict__ ws,
                                                 float* __restrict__ loss_out) {
  __shared__ float z_s[LDIM];
  const int t = threadIdx.x;
  const unsigned long long* wsl = (const unsigned long long*)(ws + WIN_OFF);
  if (blockIdx.x == 64) {
    __shared__ float red[256];
    float acc = 0.f;
    for (int b = 0; b < BATCH; ++b) {
      float r = ws[b * LDIM + t];
      #pragma unroll
      for (int s = 0; s < NVQ; ++s) {
        int w = (int)(wsl[b * NVQ + s] & 0xffffffffULL);
        float e = emb[((size_t)s * NCODES + w) * LDIM + t];
        float d = e - r;
        acc += d * d;
        r -= e;
      }
    }
    red[t] = acc;
    __syncthreads();
    for (int off = 128; off > 0; off >>= 1) {
      if (t < off) red[t] += red[t + off];
      __syncthreads();
    }
    if (t == 0) loss_out[0] = red[0] * (CC_ / (NVQ * BATCH * LDIM));
    return;
  }
  const int li = blockIdx.x & 3;
  const int b  = blockIdx.x >> 2;
  const int l  = li + 1;
  float z = 0.f;
  #pragma unroll
  for (int s = 0; s < NVQ; ++s) {
    int w = (int)(wsl[b * NVQ + s] & 0xffffffffULL);
    z += emb[((size_t)s * NCODES + w) * LDIM + t];
  }
  z_s[t] = z;
  __syncthreads();
  float m1 = mod_b[l * 2 * HID + t];
  float m2 = mod_b[l * 2 * HID + HID + t];
  const float* Wm = mod_W + (size_t)l * LDIM * 2 * HID;
  #pragma unroll 4
  for (int d = 0; d < LDIM; ++d) {
    float zd = z_s[d];
    m1 = fmaf(zd, Wm[d * 2 * HID + t], m1);
    m2 = fmaf(zd, Wm[d * 2 * HID + HID + t], m2);
  }
  float* film = ws + FILM_OFF;
  film[((b * 4 + li) * 2 + 0) * HID + t] = 1.f + m1;
  film[((b * 4 + li) * 2 + 1) * HID + t] = m2;
}

// ---------------- FAST siren: PTILE=64, 2 blocks/CU (r12-proven, unchanged) ----------------
__global__ __launch_bounds__(512) void siren_mfma_fast(
    const float* __restrict__ coords,
    const float* __restrict__ W0,
    const float* __restrict__ b0,
    const float* __restrict__ bhv,
    const float* __restrict__ Wl,
    const float* __restrict__ bl,
    const float* __restrict__ ws,
    float* __restrict__ out) {
  __shared__ short x_h[PTILE * 264];
  __shared__ short x_l[PTILE * 264];
  __shared__ float osum[PTILE * 8 * 3];
  const int tid = threadIdx.x;
  const int bp = blockIdx.x;
  const int b = bp >> 6;
  const int tile = bp & 63;
  const int pbase = b * NPTS + tile * PTILE;

  {
    const int oct = tid >> 6;
    const int p = tid & 63;
    const float c0 = coords[(size_t)(pbase + p) * 2 + 0];
    const float c1 = coords[(size_t)(pbase + p) * 2 + 1];
    const int d0 = oct * 32;
    for (int i = 0; i < 32; i += 8) {
      short8 hv, lv;
      #pragma unroll
      for (int j = 0; j < 8; ++j) {
        int d = d0 + i + j;
        float pre = fmaf(c0, W0[d], fmaf(c1, W0[HID + d], b0[d]));
        short hi, lo;
        split_trunc(__sinf(OMEGA_ * pre), hi, lo);
        hv[j] = hi; lv[j] = lo;
      }
      *(short8*)&x_h[p * 264 + d0 + i] = hv;
      *(short8*)&x_l[p * 264 + d0 + i] = lv;
    }
  }

  const int lane = tid & 63;
  const int hq = tid >> 6;
  const int hb = hq * 32;
  const int n = lane & 15;
  const int q = lane >> 4;

  const short* wp_hi = (const short*)((const char*)ws + WP_BYTE);
  const short* wp_lo = wp_hi + PLANE_SHORTS;
  const float* film = ws + FILM_OFF;

  for (int layer = 1; layer < NLAY; ++layer) {
    const int li = layer - 1;
    f32x4 acc[4][2];
    #pragma unroll
    for (int pt = 0; pt < 4; ++pt)
      #pragma unroll
      for (int ht = 0; ht < 2; ++ht)
        acc[pt][ht] = (f32x4){0.f, 0.f, 0.f, 0.f};

    __syncthreads();

    #pragma unroll 2
    for (int kc = 0; kc < HID; kc += 32) {
      const int c = kc >> 5;
      short8 Bh[2], Bl[2];
      #pragma unroll
      for (int ht = 0; ht < 2; ++ht) {
        const size_t wb = ((((size_t)li * 16 + hq * 2 + ht) * 8 + c) * 64 + lane) * 8;
        Bh[ht] = *(const short8*)&wp_hi[wb];
        Bl[ht] = *(const short8*)&wp_lo[wb];
      }
      short8 Ah[4], Al[4];
      #pragma unroll
      for (int pt = 0; pt < 4; ++pt) {
        const int xb = (pt * 16 + n) * 264 + kc + q * 8;
        Ah[pt] = *(const short8*)&x_h[xb];
        Al[pt] = *(const short8*)&x_l[xb];
      }
      #pragma unroll
      for (int ht = 0; ht < 2; ++ht)
        #pragma unroll
        for (int pt = 0; pt < 4; ++pt)
          acc[pt][ht] = __builtin_amdgcn_mfma_f32_16x16x32_bf16(Ah[pt], Bh[ht], acc[pt][ht], 0, 0, 0);
      #pragma unroll
      for (int ht = 0; ht < 2; ++ht)
        #pragma unroll
        for (int pt = 0; pt < 4; ++pt)
          acc[pt][ht] = __builtin_amdgcn_mfma_f32_16x16x32_bf16(Ah[pt], Bl[ht], acc[pt][ht], 0, 0, 0);
      #pragma unroll
      for (int ht = 0; ht < 2; ++ht)
        #pragma unroll
        for (int pt = 0; pt < 4; ++pt)
          acc[pt][ht] = __builtin_amdgcn_mfma_f32_16x16x32_bf16(Al[pt], Bh[ht], acc[pt][ht], 0, 0, 0);
    }

    __syncthreads();

    #pragma unroll
    for (int ht = 0; ht < 2; ++ht) {
      const int h = hb + ht * 16 + n;
      const float bias = bhv[li * HID + h];
      const float g1 = film[((b * 4 + li) * 2 + 0) * HID + h];
      const float bt = film[((b * 4 + li) * 2 + 1) * HID + h];
      #pragma unroll
      for (int pt = 0; pt < 4; ++pt) {
        #pragma unroll
        for (int r = 0; r < 4; ++r) {
          float pre = acc[pt][ht][r] + bias;
          pre = fmaf(pre, g1, bt);
          short hi, lo;
          split_trunc(__sinf(OMEGA_ * pre), hi, lo);
          const int row = pt * 16 + q * 4 + r;
          x_h[row * 264 + h] = hi;
          x_l[row * 264 + h] = lo;
        }
      }
    }
  }
  __syncthreads();

  {
    const int p = tid >> 3;
    const int dq = tid & 7;
    float v0 = 0.f, v1 = 0.f, v2 = 0.f;
    for (int i = 0; i < 32; ++i) {
      int d = dq * 32 + i;
      float xv = bf16_hi_f((unsigned short)x_h[p * 264 + d]) +
                 bf16_hi_f((unsigned short)x_l[p * 264 + d]);
      v0 = fmaf(xv, Wl[d * 3 + 0], v0);
      v1 = fmaf(xv, Wl[d * 3 + 1], v1);
      v2 = fmaf(xv, Wl[d * 3 + 2], v2);
    }
    osum[(p * 8 + dq) * 3 + 0] = v0;
    osum[(p * 8 + dq) * 3 + 1] = v1;
    osum[(p * 8 + dq) * 3 + 2] = v2;
  }
  __syncthreads();
  if (tid < PTILE) {
    const int p = tid;
    float v[3] = {bl[0], bl[1], bl[2]};
    #pragma unroll
    for (int dq = 0; dq < 8; ++dq)
      #pragma unroll
      for (int c = 0; c < 3; ++c) v[c] += osum[(p * 8 + dq) * 3 + c];
    size_t o = (size_t)(pbase + p) * 3;
    out[o + 0] = v[0]; out[o + 1] = v[1]; out[o + 2] = v[2];
  }
}

// ---------------- FALLBACK siren (round-8-proven; dead when ws large) ----------------
__global__ __launch_bounds__(512) void siren_mfma(
    const float* __restrict__ coords,
    const float* __restrict__ W0,
    const float* __restrict__ b0,
    const float* __restrict__ Whg,
    const float* __restrict__ bhv,
    const float* __restrict__ Wl,
    const float* __restrict__ bl,
    const float* __restrict__ ws,
    float* __restrict__ out) {
  __shared__ unsigned int x_u[128 * 260];
  __shared__ float osum[128 * 4 * 3];
  const int tid = threadIdx.x;
  const int bp = blockIdx.x;
  const int b = bp >> 5;
  const int tile = bp & 31;
  const int pbase = b * NPTS + tile * 128;
  {
    const int quarter = tid >> 7;
    const int p = tid & 127;
    const float c0 = coords[(size_t)(pbase + p) * 2 + 0];
    const float c1 = coords[(size_t)(pbase + p) * 2 + 1];
    const int d0 = quarter * 64;
    for (int i = 0; i < 64; i += 4) {
      unsigned int buf[4];
      #pragma unroll
      for (int j = 0; j < 4; ++j) {
        int d = d0 + i + j;
        float pre = fmaf(c0, W0[d], fmaf(c1, W0[HID + d], b0[d]));
        buf[j] = pack_split(__sinf(OMEGA_ * pre));
      }
      *(uint4*)&x_u[p * 260 + d0 + i] = *(uint4*)buf;
    }
  }
  const int lane = tid & 63;
  const int wv = tid >> 6;
  const int pg = wv & 1;
  const int hq = wv >> 1;
  const int pb = pg * 64;
  const int hb = hq * 64;
  const int n = lane & 15;
  const int q = lane >> 4;
  const float* film = ws + FILM_OFF;
  for (int layer = 1; layer < NLAY; ++layer) {
    const int li = layer - 1;
    f32x4 acc[4][4];
    #pragma unroll
    for (int pt = 0; pt < 4; ++pt)
      #pragma unroll
      for (int ht = 0; ht < 4; ++ht)
        acc[pt][ht] = (f32x4){0.f, 0.f, 0.f, 0.f};
    __syncthreads();
    for (int kc = 0; kc < HID; kc += 32) {
      short8 Bh[4], Bl[4];
      #pragma unroll
      for (int ht = 0; ht < 4; ++ht) {
        const float* wbase = Whg + ((size_t)(li * 256 + kc + q * 8)) * 256 + hb + ht * 16 + n;
        #pragma unroll
        for (int j = 0; j < 8; ++j) {
          short hi, lo;
          split_trunc(wbase[(size_t)j * 256], hi, lo);
          Bh[ht][j] = hi; Bl[ht][j] = lo;
        }
      }
      short8 ah[4], al[4];
      #pragma unroll
      for (int pt = 0; pt < 4; ++pt) {
        const uint4* ap = (const uint4*)&x_u[(pb + pt * 16 + n) * 260 + kc + q * 8];
        uint4 a0 = ap[0], a1 = ap[1];
        unsigned int aw[8] = {a0.x, a0.y, a0.z, a0.w, a1.x, a1.y, a1.z, a1.w};
        #pragma unroll
        for (int j = 0; j < 8; ++j) {
          ah[pt][j] = (short)(aw[j] >> 16);
          al[pt][j] = (short)(aw[j] & 0xffffu);
        }
      }
      #pragma unroll
      for (int ht = 0; ht < 4; ++ht)
        #pragma unroll
        for (int pt = 0; pt < 4; ++pt)
          acc[pt][ht] = __builtin_amdgcn_mfma_f32_16x16x32_bf16(ah[pt], Bh[ht], acc[pt][ht], 0, 0, 0);
      #pragma unroll
      for (int ht = 0; ht < 4; ++ht)
        #pragma unroll
        for (int pt = 0; pt < 4; ++pt)
          acc[pt][ht] = __builtin_amdgcn_mfma_f32_16x16x32_bf16(ah[pt], Bl[ht], acc[pt][ht], 0, 0, 0);
      #pragma unroll
      for (int ht = 0; ht < 4; ++ht)
        #pragma unroll
        for (int pt = 0; pt < 4; ++pt)
          acc[pt][ht] = __builtin_amdgcn_mfma_f32_16x16x32_bf16(al[pt], Bh[ht], acc[pt][ht], 0, 0, 0);
    }
    __syncthreads();
    #pragma unroll
    for (int ht = 0; ht < 4; ++ht) {
      const int h = hb + ht * 16 + n;
      const float bias = bhv[li * HID + h];
      const float g1 = film[((b * 4 + li) * 2 + 0) * HID + h];
      const float bt = film[((b * 4 + li) * 2 + 1) * HID + h];
      #pragma unroll
      for (int pt = 0; pt < 4; ++pt) {
        #pragma unroll
        for (int r = 0; r < 4; ++r) {
          float pre = acc[pt][ht][r] + bias;
          pre = fmaf(pre, g1, bt);
          x_u[(pb + pt * 16 + q * 4 + r) * 260 + h] = pack_split(__sinf(OMEGA_ * pre));
        }
      }
    }
  }
  __syncthreads();
  {
    const int p = tid >> 2;
    const int dq = tid & 3;
    float v0 = 0.f, v1 = 0.f, v2 = 0.f;
    for (int i = 0; i < 64; ++i) {
      int d = dq * 64 + i;
      unsigned int wrd = x_u[p * 260 + d];
      float xv = bf16_hi_f((unsigned short)(wrd >> 16)) +
                 bf16_hi_f((unsigned short)(wrd & 0xffffu));
      v0 = fmaf(xv, Wl[d * 3 + 0], v0);
      v1 = fmaf(xv, Wl[d * 3 + 1], v1);
      v2 = fmaf(xv, Wl[d * 3 + 2], v2);
    }
    osum[(p * 4 + dq) * 3 + 0] = v0;
    osum[(p * 4 + dq) * 3 + 1] = v1;
    osum[(p * 4 + dq) * 3 + 2] = v2;
  }
  __syncthreads();
  if (tid < 128) {
    const int p = tid;
    float v[3] = {bl[0], bl[1], bl[2]};
    #pragma unroll
    for (int dq = 0; dq < 4; ++dq)
      #pragma unroll
      for (int c = 0; c < 3; ++c) v[c] += osum[(p * 4 + dq) * 3 + c];
    size_t o = (size_t)(pbase + p) * 3;
    out[o + 0] = v[0]; out[o + 1] = v[1]; out[o + 2] = v[2];
  }
}

extern "C" void kernel_launch(void* const* d_in, const int* in_sizes, int n_in,
                              void* d_out, int out_size, void* d_ws, size_t ws_size,
                              hipStream_t stream) {
  (void)in_sizes; (void)n_in;
  const float* coords  = (const float*)d_in[0];
  const int*   lidx    = (const int*)d_in[1];
  const float* latents = (const float*)d_in[2];
  const float* emb     = (const float*)d_in[3];
  const float* mod_W   = (const float*)d_in[4];
  const float* mod_b   = (const float*)d_in[5];
  const float* W0      = (const float*)d_in[6];
  const float* b0      = (const float*)d_in[7];
  const float* Wh      = (const float*)d_in[8];
  const float* bh      = (const float*)d_in[9];
  const float* Wl      = (const float*)d_in[10];
  const float* bl      = (const float*)d_in[11];
  float* out = (float*)d_out;
  float* ws  = (float*)d_ws;
  float* loss_out = out + (out_size - 1);

  const bool fast = (ws_size >= FAST_WS_NEEDED);
  vq_prep_fused<<<160, 256, 0, stream>>>(lidx, latents, emb, Wh, ws, fast ? 1 : 0);
  film_loss<<<BATCH * 4 + 1, 256, 0, stream>>>(emb, mod_W, mod_b, ws, loss_out);
  if (fast)
    siren_mfma_fast<<<(BATCH * NPTS) / PTILE, 512, 0, stream>>>(coords, W0, b0, bh, Wl, bl, ws, out);
  else
    siren_mfma<<<(BATCH * NPTS) / 128, 512, 0, stream>>>(coords, W0, b0, Wh, bh, Wl, bl, ws, out);
}

// Round 15
// 258.598 us; speedup vs baseline: 1.2444x; 1.0766x over previous
//
#include <hip/hip_runtime.h>
#include <math.h>

#define LDIM 256
#define NCODES 1024
#define HID 256
#define NLAY 5
#define NVQ 4
#define CC_ 0.25f
#define OMEGA_ 30.0f
#define BATCH 16
#define NPTS 4096
#define PTILE 64    // siren points/block (74 KB LDS -> 2 blocks/CU, r12/r13-proven)

// ws layout (float indices):
//   [4224 .. 5247] VQ stage partials u64[16][4][8] (mono_dist<<32 | idx)
//   [5280 .. 5287] barrier counters u32[8] (stages 0..3)
//   [5288]         init flag u32
//   [5289]         done counter u32 (replay-safe self-reset)
//   [8192 .. 40959] FiLM params
//   fast path (ws_size >= 1,245,184 -- PROVEN r10-r13):
//   bytes [196608..720895] wpf_hi, [720896..1245183] wpf_lo (fragment-linear)
#define PART_OFF 4224
#define CNT_OFF 5280
#define FLAG_OFF 5288
#define DONE_OFF 5289
#define FILM_OFF 8192
#define WP_BYTE 196608
#define PLANE_SHORTS (4 * 16 * 8 * 64 * 8)
#define FAST_WS_NEEDED 1245184u
#define MAGIC_ 0x13572468u

typedef __attribute__((ext_vector_type(8))) short short8;
typedef __attribute__((ext_vector_type(4))) float f32x4;

__device__ __forceinline__ unsigned int pack_split(float x) {
  unsigned int u = __builtin_bit_cast(unsigned int, x);
  float hf = __builtin_bit_cast(float, u & 0xffff0000u);
  float lf = x - hf;
  unsigned int ul = __builtin_bit_cast(unsigned int, lf);
  return (u & 0xffff0000u) | (ul >> 16);
}
__device__ __forceinline__ void split_trunc(float x, short& hi, short& lo) {
  unsigned int u = __builtin_bit_cast(unsigned int, x);
  float hf = __builtin_bit_cast(float, u & 0xffff0000u);
  float lf = x - hf;
  hi = (short)(u >> 16);
  lo = (short)(__builtin_bit_cast(unsigned int, lf) >> 16);
}
__device__ __forceinline__ float bf16_hi_f(unsigned short h) {
  return __builtin_bit_cast(float, (unsigned int)h << 16);
}
__device__ __forceinline__ unsigned int mono_u32(float f) {
  unsigned int u = __builtin_bit_cast(unsigned int, f);
  return (u & 0x80000000u) ? ~u : (u | 0x80000000u);
}

// ---------------- fused_pre: prep_w (blk 0..31) + VQ w/ REPLAY-SAFE device
// barriers (blk 32..159) + FiLM/loss duty after final barrier.
// Replay safety: flag is reset to 0 by the LAST block of each launch, so the
// init-wait is armed on every launch (fresh poison OR graph replay) and block
// 0 always zeroes counters strictly before any other block touches them.
__global__ __launch_bounds__(256) void fused_pre(
    const int* __restrict__ lidx,
    const float* __restrict__ latents,
    const float* __restrict__ emb,
    const float* __restrict__ Whg,
    const float* __restrict__ mod_W,
    const float* __restrict__ mod_b,
    float* __restrict__ ws,
    float* __restrict__ loss_out,
    int do_prep) {
  const int blk = blockIdx.x;
  const int t = threadIdx.x;

  if (blk < 32) {   // ---- prep_w duty ----
    if (!do_prep) return;
    const int li = blk >> 3;
    const int c  = blk & 7;
    const int lane = t & 63;
    const int n = lane & 15, q = lane >> 4;
    short* wp_hi = (short*)((char*)ws + WP_BYTE);
    short* wp_lo = wp_hi + PLANE_SHORTS;
    for (int h_t = (t >> 6); h_t < 16; h_t += 4) {
      short8 hv, lv;
      #pragma unroll
      for (int j = 0; j < 8; ++j) {
        float x = Whg[((size_t)(li * 256 + c * 32 + q * 8 + j)) * 256 + h_t * 16 + n];
        short hi, lo;
        split_trunc(x, hi, lo);
        hv[j] = hi; lv[j] = lo;
      }
      size_t off = ((((size_t)li * 16 + h_t) * 8 + c) * 64 + lane) * 8;
      *(short8*)&wp_hi[off] = hv;
      *(short8*)&wp_lo[off] = lv;
    }
    return;
  }

  // ---- VQ duty ----
  __shared__ __align__(16) float Ech[128 * 260];   // 133,120 B
  __shared__ __align__(16) float r_s[LDIM];
  __shared__ float mval[256];
  __shared__ int   midx[256];
  __shared__ int   bcast;
  const int vqb = blk - 32;
  const int b = vqb >> 3;
  const int slice = vqb & 7;
  unsigned int* cnt  = (unsigned int*)(ws + CNT_OFF);
  unsigned int* flag = (unsigned int*)(ws + FLAG_OFF);
  unsigned int* done = (unsigned int*)(ws + DONE_OFF);
  unsigned long long* part = (unsigned long long*)(ws + PART_OFF);

  if (vqb == 0 && t == 0) {   // init: zero counters, THEN publish flag
    #pragma unroll
    for (int i = 0; i < 8; ++i)
      __hip_atomic_store(&cnt[i], 0u, __ATOMIC_RELAXED, __HIP_MEMORY_SCOPE_AGENT);
    __hip_atomic_store(done, 0u, __ATOMIC_RELAXED, __HIP_MEMORY_SCOPE_AGENT);
    __hip_atomic_store(flag, MAGIC_, __ATOMIC_RELEASE, __HIP_MEMORY_SCOPE_AGENT);
  }

  {
    const int ib = lidx[b];
    float z = 0.f;
    #pragma unroll
    for (int v = 0; v < NVQ; ++v) z += latents[((size_t)ib * NVQ + v) * LDIM + t];
    r_s[t] = z;
  }
  if (t == 0) {   // armed on EVERY launch (flag==0 after replay, 0xAA.. after poison)
    int guard = 0;
    while (__hip_atomic_load(flag, __ATOMIC_ACQUIRE, __HIP_MEMORY_SCOPE_AGENT) != MAGIC_
           && guard < (1 << 22)) { __builtin_amdgcn_s_sleep(8); ++guard; }
  }
  __syncthreads();

  const int cg = t >> 3;   // code slot 0..31
  const int dq = t & 7;    // dim octant

  for (int s = 0; s < NVQ; ++s) {
    const float* E = emb + (size_t)s * NCODES * LDIM + (size_t)slice * 128 * LDIM;
    const float4* E4 = (const float4*)E;
    #pragma unroll 8
    for (int it = 0; it < 32; ++it) {
      int row = it * 4 + (t >> 6);
      int col4 = t & 63;
      *(float4*)&Ech[row * 260 + col4 * 4] = E4[(size_t)row * 64 + col4];
    }
    __syncthreads();
    float bestv = 3.4e38f; int besti = 0;
    for (int cp = 0; cp < 4; ++cp) {        // ascending -> strict < keeps first idx
      const int cl = cp * 32 + cg;
      const float* er = &Ech[cl * 260];
      const float4* rr4 = (const float4*)r_s;
      float dot = 0.f, e2 = 0.f;
      #pragma unroll
      for (int j = 0; j < 8; ++j) {
        int d4 = dq + 8 * j;
        float4 e = *(const float4*)&er[d4 * 4];
        float4 rv = rr4[d4];
        dot += e.x * rv.x + e.y * rv.y + e.z * rv.z + e.w * rv.w;
        e2  += e.x * e.x + e.y * e.y + e.z * e.z + e.w * e.w;
      }
      dot += __shfl_xor(dot, 1); e2 += __shfl_xor(e2, 1);
      dot += __shfl_xor(dot, 2); e2 += __shfl_xor(e2, 2);
      dot += __shfl_xor(dot, 4); e2 += __shfl_xor(e2, 4);
      if (dq == 0) {
        float dist = e2 - 2.f * dot;        // +||r||^2 constant: argmin-invariant
        if (dist < bestv) { bestv = dist; besti = slice * 128 + cl; }
      }
    }
    mval[t] = (dq == 0) ? bestv : 3.4e38f;
    midx[t] = (dq == 0) ? besti : (1 << 30);
    __syncthreads();
    for (int off = 128; off > 0; off >>= 1) {
      if (t < off) {
        float ov = mval[t + off]; int oi = midx[t + off];
        if (ov < mval[t] || (ov == mval[t] && oi < midx[t])) { mval[t] = ov; midx[t] = oi; }
      }
      __syncthreads();
    }
    if (t == 0) {
      unsigned long long pack =
          ((unsigned long long)mono_u32(mval[0]) << 32) | (unsigned int)midx[0];
      __hip_atomic_store(&part[(b * NVQ + s) * 8 + slice], pack,
                         __ATOMIC_RELAXED, __HIP_MEMORY_SCOPE_AGENT);
      __hip_atomic_fetch_add(&cnt[s], 1u, __ATOMIC_RELEASE, __HIP_MEMORY_SCOPE_AGENT);
      int guard = 0;
      while (__hip_atomic_load(&cnt[s], __ATOMIC_ACQUIRE, __HIP_MEMORY_SCOPE_AGENT) < 128u
             && guard < (1 << 22)) { __builtin_amdgcn_s_sleep(8); ++guard; }
      unsigned long long best =
          __hip_atomic_load(&part[(b * NVQ + s) * 8 + 0], __ATOMIC_RELAXED, __HIP_MEMORY_SCOPE_AGENT);
      #pragma unroll
      for (int s2 = 1; s2 < 8; ++s2) {
        unsigned long long v =
            __hip_atomic_load(&part[(b * NVQ + s) * 8 + s2], __ATOMIC_RELAXED, __HIP_MEMORY_SCOPE_AGENT);
        if (v < best) best = v;   // u64 min == lexicographic (dist, first idx)
      }
      bcast = (int)(best & 0xffffffffULL);
    }
    __syncthreads();
    if (s < NVQ - 1) r_s[t] -= emb[((size_t)s * NCODES + bcast) * LDIM + t];
    __syncthreads();
  }

  // ---- post-barrier film/loss duty ----
  if (vqb < 64) {        // film for (fb, li)
    const int fb = vqb >> 2;
    const int li = vqb & 3;
    const int l  = li + 1;
    int w[NVQ];
    #pragma unroll
    for (int s = 0; s < NVQ; ++s) {
      unsigned long long best =
          __hip_atomic_load(&part[(fb * NVQ + s) * 8 + 0], __ATOMIC_RELAXED, __HIP_MEMORY_SCOPE_AGENT);
      #pragma unroll
      for (int s2 = 1; s2 < 8; ++s2) {
        unsigned long long v =
            __hip_atomic_load(&part[(fb * NVQ + s) * 8 + s2], __ATOMIC_RELAXED, __HIP_MEMORY_SCOPE_AGENT);
        if (v < best) best = v;
      }
      w[s] = (int)(best & 0xffffffffULL);
    }
    float z = 0.f;
    #pragma unroll
    for (int s = 0; s < NVQ; ++s)
      z += emb[((size_t)s * NCODES + w[s]) * LDIM + t];   // effective_z
    __syncthreads();
    r_s[t] = z;          // reuse as z_s
    __syncthreads();
    float m1 = mod_b[l * 2 * HID + t];
    float m2 = mod_b[l * 2 * HID + HID + t];
    const float* Wm = mod_W + (size_t)l * LDIM * 2 * HID;
    #pragma unroll 4
    for (int d = 0; d < LDIM; ++d) {
      float zd = r_s[d];
      m1 = fmaf(zd, Wm[d * 2 * HID + t], m1);
      m2 = fmaf(zd, Wm[d * 2 * HID + HID + t], m2);
    }
    float* film = ws + FILM_OFF;
    film[((fb * 4 + li) * 2 + 0) * HID + t] = 1.f + m1;
    film[((fb * 4 + li) * 2 + 1) * HID + t] = m2;
  } else if (vqb == 64) {   // loss
    float acc = 0.f;
    for (int bb = 0; bb < BATCH; ++bb) {
      int w[NVQ];
      #pragma unroll
      for (int s = 0; s < NVQ; ++s) {
        unsigned long long best =
            __hip_atomic_load(&part[(bb * NVQ + s) * 8 + 0], __ATOMIC_RELAXED, __HIP_MEMORY_SCOPE_AGENT);
        #pragma unroll
        for (int s2 = 1; s2 < 8; ++s2) {
          unsigned long long v =
              __hip_atomic_load(&part[(bb * NVQ + s) * 8 + s2], __ATOMIC_RELAXED, __HIP_MEMORY_SCOPE_AGENT);
          if (v < best) best = v;
        }
        w[s] = (int)(best & 0xffffffffULL);
      }
      const int ibb = lidx[bb];
      float r = 0.f;
      #pragma unroll
      for (int v = 0; v < NVQ; ++v) r += latents[((size_t)ibb * NVQ + v) * LDIM + t];
      #pragma unroll
      for (int s = 0; s < NVQ; ++s) {
        float e = emb[((size_t)s * NCODES + w[s]) * LDIM + t];
        float d = e - r;
        acc += d * d;
        r -= e;
      }
    }
    __syncthreads();
    mval[t] = acc;
    __syncthreads();
    for (int off = 128; off > 0; off >>= 1) {
      if (t < off) mval[t] += mval[t + off];
      __syncthreads();
    }
    if (t == 0) loss_out[0] = mval[0] * (CC_ / (NVQ * BATCH * LDIM));
  }

  // ---- replay-safe teardown: last of 128 VQ blocks resets barrier state ----
  __syncthreads();   // all this block's work (incl. film/loss stores) issued
  if (t == 0) {
    unsigned int prev =
        __hip_atomic_fetch_add(done, 1u, __ATOMIC_ACQ_REL, __HIP_MEMORY_SCOPE_AGENT);
    if (prev == 127u) {   // last block out: rearm for next launch/replay
      #pragma unroll
      for (int i = 0; i < 8; ++i)
        __hip_atomic_store(&cnt[i], 0u, __ATOMIC_RELAXED, __HIP_MEMORY_SCOPE_AGENT);
      __hip_atomic_store(done, 0u, __ATOMIC_RELAXED, __HIP_MEMORY_SCOPE_AGENT);
      __hip_atomic_store(flag, 0u, __ATOMIC_RELEASE, __HIP_MEMORY_SCOPE_AGENT);
    }
  }
}

// ---------------- FAST siren: PTILE=64, 2 blocks/CU (r12/r13-proven, unchanged) ----------------
__global__ __launch_bounds__(512) void siren_mfma_fast(
    const float* __restrict__ coords,
    const float* __restrict__ W0,
    const float* __restrict__ b0,
    const float* __restrict__ bhv,
    const float* __restrict__ Wl,
    const float* __restrict__ bl,
    const float* __restrict__ ws,
    float* __restrict__ out) {
  __shared__ short x_h[PTILE * 264];
  __shared__ short x_l[PTILE * 264];
  __shared__ float osum[PTILE * 8 * 3];
  const int tid = threadIdx.x;
  const int bp = blockIdx.x;
  const int b = bp >> 6;
  const int tile = bp & 63;
  const int pbase = b * NPTS + tile * PTILE;

  {
    const int oct = tid >> 6;
    const int p = tid & 63;
    const float c0 = coords[(size_t)(pbase + p) * 2 + 0];
    const float c1 = coords[(size_t)(pbase + p) * 2 + 1];
    const int d0 = oct * 32;
    for (int i = 0; i < 32; i += 8) {
      short8 hv, lv;
      #pragma unroll
      for (int j = 0; j < 8; ++j) {
        int d = d0 + i + j;
        float pre = fmaf(c0, W0[d], fmaf(c1, W0[HID + d], b0[d]));
        short hi, lo;
        split_trunc(__sinf(OMEGA_ * pre), hi, lo);
        hv[j] = hi; lv[j] = lo;
      }
      *(short8*)&x_h[p * 264 + d0 + i] = hv;
      *(short8*)&x_l[p * 264 + d0 + i] = lv;
    }
  }

  const int lane = tid & 63;
  const int hq = tid >> 6;
  const int hb = hq * 32;
  const int n = lane & 15;
  const int q = lane >> 4;

  const short* wp_hi = (const short*)((const char*)ws + WP_BYTE);
  const short* wp_lo = wp_hi + PLANE_SHORTS;
  const float* film = ws + FILM_OFF;

  for (int layer = 1; layer < NLAY; ++layer) {
    const int li = layer - 1;
    f32x4 acc[4][2];
    #pragma unroll
    for (int pt = 0; pt < 4; ++pt)
      #pragma unroll
      for (int ht = 0; ht < 2; ++ht)
        acc[pt][ht] = (f32x4){0.f, 0.f, 0.f, 0.f};

    __syncthreads();

    #pragma unroll 2
    for (int kc = 0; kc < HID; kc += 32) {
      const int c = kc >> 5;
      short8 Bh[2], Bl[2];
      #pragma unroll
      for (int ht = 0; ht < 2; ++ht) {
        const size_t wb = ((((size_t)li * 16 + hq * 2 + ht) * 8 + c) * 64 + lane) * 8;
        Bh[ht] = *(const short8*)&wp_hi[wb];
        Bl[ht] = *(const short8*)&wp_lo[wb];
      }
      short8 Ah[4], Al[4];
      #pragma unroll
      for (int pt = 0; pt < 4; ++pt) {
        const int xb = (pt * 16 + n) * 264 + kc + q * 8;
        Ah[pt] = *(const short8*)&x_h[xb];
        Al[pt] = *(const short8*)&x_l[xb];
      }
      #pragma unroll
      for (int ht = 0; ht < 2; ++ht)
        #pragma unroll
        for (int pt = 0; pt < 4; ++pt)
          acc[pt][ht] = __builtin_amdgcn_mfma_f32_16x16x32_bf16(Ah[pt], Bh[ht], acc[pt][ht], 0, 0, 0);
      #pragma unroll
      for (int ht = 0; ht < 2; ++ht)
        #pragma unroll
        for (int pt = 0; pt < 4; ++pt)
          acc[pt][ht] = __builtin_amdgcn_mfma_f32_16x16x32_bf16(Ah[pt], Bl[ht], acc[pt][ht], 0, 0, 0);
      #pragma unroll
      for (int ht = 0; ht < 2; ++ht)
        #pragma unroll
        for (int pt = 0; pt < 4; ++pt)
          acc[pt][ht] = __builtin_amdgcn_mfma_f32_16x16x32_bf16(Al[pt], Bh[ht], acc[pt][ht], 0, 0, 0);
    }

    __syncthreads();

    #pragma unroll
    for (int ht = 0; ht < 2; ++ht) {
      const int h = hb + ht * 16 + n;
      const float bias = bhv[li * HID + h];
      const float g1 = film[((b * 4 + li) * 2 + 0) * HID + h];
      const float bt = film[((b * 4 + li) * 2 + 1) * HID + h];
      #pragma unroll
      for (int pt = 0; pt < 4; ++pt) {
        #pragma unroll
        for (int r = 0; r < 4; ++r) {
          float pre = acc[pt][ht][r] + bias;
          pre = fmaf(pre, g1, bt);
          short hi, lo;
          split_trunc(__sinf(OMEGA_ * pre), hi, lo);
          const int row = pt * 16 + q * 4 + r;
          x_h[row * 264 + h] = hi;
          x_l[row * 264 + h] = lo;
        }
      }
    }
  }
  __syncthreads();

  {
    const int p = tid >> 3;
    const int dq = tid & 7;
    float v0 = 0.f, v1 = 0.f, v2 = 0.f;
    for (int i = 0; i < 32; ++i) {
      int d = dq * 32 + i;
      float xv = bf16_hi_f((unsigned short)x_h[p * 264 + d]) +
                 bf16_hi_f((unsigned short)x_l[p * 264 + d]);
      v0 = fmaf(xv, Wl[d * 3 + 0], v0);
      v1 = fmaf(xv, Wl[d * 3 + 1], v1);
      v2 = fmaf(xv, Wl[d * 3 + 2], v2);
    }
    osum[(p * 8 + dq) * 3 + 0] = v0;
    osum[(p * 8 + dq) * 3 + 1] = v1;
    osum[(p * 8 + dq) * 3 + 2] = v2;
  }
  __syncthreads();
  if (tid < PTILE) {
    const int p = tid;
    float v[3] = {bl[0], bl[1], bl[2]};
    #pragma unroll
    for (int dq = 0; dq < 8; ++dq)
      #pragma unroll
      for (int c = 0; c < 3; ++c) v[c] += osum[(p * 8 + dq) * 3 + c];
    size_t o = (size_t)(pbase + p) * 3;
    out[o + 0] = v[0]; out[o + 1] = v[1]; out[o + 2] = v[2];
  }
}

// ---------------- FALLBACK siren (round-8-proven; dead when ws large) ----------------
__global__ __launch_bounds__(512) void siren_mfma(
    const float* __restrict__ coords,
    const float* __restrict__ W0,
    const float* __restrict__ b0,
    const float* __restrict__ Whg,
    const float* __restrict__ bhv,
    const float* __restrict__ Wl,
    const float* __restrict__ bl,
    const float* __restrict__ ws,
    float* __restrict__ out) {
  __shared__ unsigned int x_u[128 * 260];
  __shared__ float osum[128 * 4 * 3];
  const int tid = threadIdx.x;
  const int bp = blockIdx.x;
  const int b = bp >> 5;
  const int tile = bp & 31;
  const int pbase = b * NPTS + tile * 128;
  {
    const int quarter = tid >> 7;
    const int p = tid & 127;
    const float c0 = coords[(size_t)(pbase + p) * 2 + 0];
    const float c1 = coords[(size_t)(pbase + p) * 2 + 1];
    const int d0 = quarter * 64;
    for (int i = 0; i < 64; i += 4) {
      unsigned int buf[4];
      #pragma unroll
      for (int j = 0; j < 4; ++j) {
        int d = d0 + i + j;
        float pre = fmaf(c0, W0[d], fmaf(c1, W0[HID + d], b0[d]));
        buf[j] = pack_split(__sinf(OMEGA_ * pre));
      }
      *(uint4*)&x_u[p * 260 + d0 + i] = *(uint4*)buf;
    }
  }
  const int lane = tid & 63;
  const int wv = tid >> 6;
  const int pg = wv & 1;
  const int hq = wv >> 1;
  const int pb = pg * 64;
  const int hb = hq * 64;
  const int n = lane & 15;
  const int q = lane >> 4;
  const float* film = ws + FILM_OFF;
  for (int layer = 1; layer < NLAY; ++layer) {
    const int li = layer - 1;
    f32x4 acc[4][4];
    #pragma unroll
    for (int pt = 0; pt < 4; ++pt)
      #pragma unroll
      for (int ht = 0; ht < 4; ++ht)
        acc[pt][ht] = (f32x4){0.f, 0.f, 0.f, 0.f};
    __syncthreads();
    for (int kc = 0; kc < HID; kc += 32) {
      short8 Bh[4], Bl[4];
      #pragma unroll
      for (int ht = 0; ht < 4; ++ht) {
        const float* wbase = Whg + ((size_t)(li * 256 + kc + q * 8)) * 256 + hb + ht * 16 + n;
        #pragma unroll
        for (int j = 0; j < 8; ++j) {
          short hi, lo;
          split_trunc(wbase[(size_t)j * 256], hi, lo);
          Bh[ht][j] = hi; Bl[ht][j] = lo;
        }
      }
      short8 ah[4], al[4];
      #pragma unroll
      for (int pt = 0; pt < 4; ++pt) {
        const uint4* ap = (const uint4*)&x_u[(pb + pt * 16 + n) * 260 + kc + q * 8];
        uint4 a0 = ap[0], a1 = ap[1];
        unsigned int aw[8] = {a0.x, a0.y, a0.z, a0.w, a1.x, a1.y, a1.z, a1.w};
        #pragma unroll
        for (int j = 0; j < 8; ++j) {
          ah[pt][j] = (short)(aw[j] >> 16);
          al[pt][j] = (short)(aw[j] & 0xffffu);
        }
      }
      #pragma unroll
      for (int ht = 0; ht < 4; ++ht)
        #pragma unroll
        for (int pt = 0; pt < 4; ++pt)
          acc[pt][ht] = __builtin_amdgcn_mfma_f32_16x16x32_bf16(ah[pt], Bh[ht], acc[pt][ht], 0, 0, 0);
      #pragma unroll
      for (int ht = 0; ht < 4; ++ht)
        #pragma unroll
        for (int pt = 0; pt < 4; ++pt)
          acc[pt][ht] = __builtin_amdgcn_mfma_f32_16x16x32_bf16(ah[pt], Bl[ht], acc[pt][ht], 0, 0, 0);
      #pragma unroll
      for (int ht = 0; ht < 4; ++ht)
        #pragma unroll
        for (int pt = 0; pt < 4; ++pt)
          acc[pt][ht] = __builtin_amdgcn_mfma_f32_16x16x32_bf16(al[pt], Bh[ht], acc[pt][ht], 0, 0, 0);
    }
    __syncthreads();
    #pragma unroll
    for (int ht = 0; ht < 4; ++ht) {
      const int h = hb + ht * 16 + n;
      const float bias = bhv[li * HID + h];
      const float g1 = film[((b * 4 + li) * 2 + 0) * HID + h];
      const float bt = film[((b * 4 + li) * 2 + 1) * HID + h];
      #pragma unroll
      for (int pt = 0; pt < 4; ++pt) {
        #pragma unroll
        for (int r = 0; r < 4; ++r) {
          float pre = acc[pt][ht][r] + bias;
          pre = fmaf(pre, g1, bt);
          x_u[(pb + pt * 16 + q * 4 + r) * 260 + h] = pack_split(__sinf(OMEGA_ * pre));
        }
      }
    }
  }
  __syncthreads();
  {
    const int p = tid >> 2;
    const int dq = tid & 3;
    float v0 = 0.f, v1 = 0.f, v2 = 0.f;
    for (int i = 0; i < 64; ++i) {
      int d = dq * 64 + i;
      unsigned int wrd = x_u[p * 260 + d];
      float xv = bf16_hi_f((unsigned short)(wrd >> 16)) +
                 bf16_hi_f((unsigned short)(wrd & 0xffffu));
      v0 = fmaf(xv, Wl[d * 3 + 0], v0);
      v1 = fmaf(xv, Wl[d * 3 + 1], v1);
      v2 = fmaf(xv, Wl[d * 3 + 2], v2);
    }
    osum[(p * 4 + dq) * 3 + 0] = v0;
    osum[(p * 4 + dq) * 3 + 1] = v1;
    osum[(p * 4 + dq) * 3 + 2] = v2;
  }
  __syncthreads();
  if (tid < 128) {
    const int p = tid;
    float v[3] = {bl[0], bl[1], bl[2]};
    #pragma unroll
    for (int dq = 0; dq < 4; ++dq)
      #pragma unroll
      for (int c = 0; c < 3; ++c) v[c] += osum[(p * 4 + dq) * 3 + c];
    size_t o = (size_t)(pbase + p) * 3;
    out[o + 0] = v[0]; out[o + 1] = v[1]; out[o + 2] = v[2];
  }
}

extern "C" void kernel_launch(void* const* d_in, const int* in_sizes, int n_in,
                              void* d_out, int out_size, void* d_ws, size_t ws_size,
                              hipStream_t stream) {
  (void)in_sizes; (void)n_in;
  const float* coords  = (const float*)d_in[0];
  const int*   lidx    = (const int*)d_in[1];
  const float* latents = (const float*)d_in[2];
  const float* emb     = (const float*)d_in[3];
  const float* mod_W   = (const float*)d_in[4];
  const float* mod_b   = (const float*)d_in[5];
  const float* W0      = (const float*)d_in[6];
  const float* b0      = (const float*)d_in[7];
  const float* Wh      = (const float*)d_in[8];
  const float* bh      = (const float*)d_in[9];
  const float* Wl      = (const float*)d_in[10];
  const float* bl      = (const float*)d_in[11];
  float* out = (float*)d_out;
  float* ws  = (float*)d_ws;
  float* loss_out = out + (out_size - 1);

  const bool fast = (ws_size >= FAST_WS_NEEDED);
  fused_pre<<<160, 256, 0, stream>>>(lidx, latents, emb, Wh, mod_W, mod_b, ws,
                                     loss_out, fast ? 1 : 0);
  if (fast)
    siren_mfma_fast<<<(BATCH * NPTS) / PTILE, 512, 0, stream>>>(coords, W0, b0, bh, Wl, bl, ws, out);
  else
    siren_mfma<<<(BATCH * NPTS) / 128, 512, 0, stream>>>(coords, W0, b0, Wh, bh, Wl, bl, ws, out);
}

// Round 16
// 252.697 us; speedup vs baseline: 1.2734x; 1.0234x over previous
//
#include <hip/hip_runtime.h>
#include <math.h>

#define LDIM 256
#define NCODES 1024
#define HID 256
#define NLAY 5
#define NVQ 4
#define CC_ 0.25f
#define OMEGA_ 30.0f
#define BATCH 16
#define NPTS 4096
#define PTILE 64    // siren points/block (74 KB LDS -> 2 blocks/CU, r12-r15-proven)

// ws layout (float indices):
//   [4224 .. 5247] VQ stage partials u64[16][4][8] (mono_dist<<32 | idx)
//   [5280 .. 5287] barrier counters u32[8] (stages 0..3)
//   [5288]         init flag u32
//   [5289]         done counter u32 (replay-safe self-reset)
//   [8192 .. 40959] FiLM params
//   fast path (ws_size >= 1,245,184 -- PROVEN r10-r15):
//   bytes [196608..720895] wpf_hi, [720896..1245183] wpf_lo (fragment-linear)
#define PART_OFF 4224
#define CNT_OFF 5280
#define FLAG_OFF 5288
#define DONE_OFF 5289
#define FILM_OFF 8192
#define WP_BYTE 196608
#define PLANE_SHORTS (4 * 16 * 8 * 64 * 8)
#define FAST_WS_NEEDED 1245184u
#define MAGIC_ 0x13572468u

typedef __attribute__((ext_vector_type(8))) short short8;
typedef __attribute__((ext_vector_type(4))) float f32x4;

__device__ __forceinline__ unsigned int pack_split(float x) {
  unsigned int u = __builtin_bit_cast(unsigned int, x);
  float hf = __builtin_bit_cast(float, u & 0xffff0000u);
  float lf = x - hf;
  unsigned int ul = __builtin_bit_cast(unsigned int, lf);
  return (u & 0xffff0000u) | (ul >> 16);
}
__device__ __forceinline__ void split_trunc(float x, short& hi, short& lo) {
  unsigned int u = __builtin_bit_cast(unsigned int, x);
  float hf = __builtin_bit_cast(float, u & 0xffff0000u);
  float lf = x - hf;
  hi = (short)(u >> 16);
  lo = (short)(__builtin_bit_cast(unsigned int, lf) >> 16);
}
__device__ __forceinline__ float bf16_hi_f(unsigned short h) {
  return __builtin_bit_cast(float, (unsigned int)h << 16);
}
__device__ __forceinline__ unsigned int mono_u32(float f) {
  unsigned int u = __builtin_bit_cast(unsigned int, f);
  return (u & 0x80000000u) ? ~u : (u | 0x80000000u);
}

// ---------------- fused_pre: prep_w + VQ (replay-safe device barriers) + film/loss.
// r16 change: spin loops poll RELAXED (no per-poll L1/L2 invalidation on
// non-coherent-XCD gfx950), then ONE acquire load after exit establishes
// synchronizes-with via the release sequence on the counter/flag.
__global__ __launch_bounds__(256) void fused_pre(
    const int* __restrict__ lidx,
    const float* __restrict__ latents,
    const float* __restrict__ emb,
    const float* __restrict__ Whg,
    const float* __restrict__ mod_W,
    const float* __restrict__ mod_b,
    float* __restrict__ ws,
    float* __restrict__ loss_out,
    int do_prep) {
  const int blk = blockIdx.x;
  const int t = threadIdx.x;

  if (blk < 32) {   // ---- prep_w duty ----
    if (!do_prep) return;
    const int li = blk >> 3;
    const int c  = blk & 7;
    const int lane = t & 63;
    const int n = lane & 15, q = lane >> 4;
    short* wp_hi = (short*)((char*)ws + WP_BYTE);
    short* wp_lo = wp_hi + PLANE_SHORTS;
    for (int h_t = (t >> 6); h_t < 16; h_t += 4) {
      short8 hv, lv;
      #pragma unroll
      for (int j = 0; j < 8; ++j) {
        float x = Whg[((size_t)(li * 256 + c * 32 + q * 8 + j)) * 256 + h_t * 16 + n];
        short hi, lo;
        split_trunc(x, hi, lo);
        hv[j] = hi; lv[j] = lo;
      }
      size_t off = ((((size_t)li * 16 + h_t) * 8 + c) * 64 + lane) * 8;
      *(short8*)&wp_hi[off] = hv;
      *(short8*)&wp_lo[off] = lv;
    }
    return;
  }

  // ---- VQ duty ----
  __shared__ __align__(16) float Ech[128 * 260];   // 133,120 B
  __shared__ __align__(16) float r_s[LDIM];
  __shared__ float mval[256];
  __shared__ int   midx[256];
  __shared__ int   bcast;
  const int vqb = blk - 32;
  const int b = vqb >> 3;
  const int slice = vqb & 7;
  unsigned int* cnt  = (unsigned int*)(ws + CNT_OFF);
  unsigned int* flag = (unsigned int*)(ws + FLAG_OFF);
  unsigned int* done = (unsigned int*)(ws + DONE_OFF);
  unsigned long long* part = (unsigned long long*)(ws + PART_OFF);

  if (vqb == 0 && t == 0) {   // init: zero counters, THEN publish flag
    #pragma unroll
    for (int i = 0; i < 8; ++i)
      __hip_atomic_store(&cnt[i], 0u, __ATOMIC_RELAXED, __HIP_MEMORY_SCOPE_AGENT);
    __hip_atomic_store(done, 0u, __ATOMIC_RELAXED, __HIP_MEMORY_SCOPE_AGENT);
    __hip_atomic_store(flag, MAGIC_, __ATOMIC_RELEASE, __HIP_MEMORY_SCOPE_AGENT);
  }

  {
    const int ib = lidx[b];
    float z = 0.f;
    #pragma unroll
    for (int v = 0; v < NVQ; ++v) z += latents[((size_t)ib * NVQ + v) * LDIM + t];
    r_s[t] = z;
  }
  if (t == 0) {   // armed on EVERY launch; RELAXED poll, single acquire after
    int guard = 0;
    while (__hip_atomic_load(flag, __ATOMIC_RELAXED, __HIP_MEMORY_SCOPE_AGENT) != MAGIC_
           && guard < (1 << 22)) { __builtin_amdgcn_s_sleep(8); ++guard; }
    (void)__hip_atomic_load(flag, __ATOMIC_ACQUIRE, __HIP_MEMORY_SCOPE_AGENT);
  }
  __syncthreads();

  const int cg = t >> 3;   // code slot 0..31
  const int dq = t & 7;    // dim octant

  for (int s = 0; s < NVQ; ++s) {
    const float* E = emb + (size_t)s * NCODES * LDIM + (size_t)slice * 128 * LDIM;
    const float4* E4 = (const float4*)E;
    #pragma unroll 8
    for (int it = 0; it < 32; ++it) {
      int row = it * 4 + (t >> 6);
      int col4 = t & 63;
      *(float4*)&Ech[row * 260 + col4 * 4] = E4[(size_t)row * 64 + col4];
    }
    __syncthreads();
    float bestv = 3.4e38f; int besti = 0;
    for (int cp = 0; cp < 4; ++cp) {        // ascending -> strict < keeps first idx
      const int cl = cp * 32 + cg;
      const float* er = &Ech[cl * 260];
      const float4* rr4 = (const float4*)r_s;
      float dot = 0.f, e2 = 0.f;
      #pragma unroll
      for (int j = 0; j < 8; ++j) {
        int d4 = dq + 8 * j;
        float4 e = *(const float4*)&er[d4 * 4];
        float4 rv = rr4[d4];
        dot += e.x * rv.x + e.y * rv.y + e.z * rv.z + e.w * rv.w;
        e2  += e.x * e.x + e.y * e.y + e.z * e.z + e.w * e.w;
      }
      dot += __shfl_xor(dot, 1); e2 += __shfl_xor(e2, 1);
      dot += __shfl_xor(dot, 2); e2 += __shfl_xor(e2, 2);
      dot += __shfl_xor(dot, 4); e2 += __shfl_xor(e2, 4);
      if (dq == 0) {
        float dist = e2 - 2.f * dot;        // +||r||^2 constant: argmin-invariant
        if (dist < bestv) { bestv = dist; besti = slice * 128 + cl; }
      }
    }
    mval[t] = (dq == 0) ? bestv : 3.4e38f;
    midx[t] = (dq == 0) ? besti : (1 << 30);
    __syncthreads();
    for (int off = 128; off > 0; off >>= 1) {
      if (t < off) {
        float ov = mval[t + off]; int oi = midx[t + off];
        if (ov < mval[t] || (ov == mval[t] && oi < midx[t])) { mval[t] = ov; midx[t] = oi; }
      }
      __syncthreads();
    }
    if (t == 0) {
      unsigned long long pack =
          ((unsigned long long)mono_u32(mval[0]) << 32) | (unsigned int)midx[0];
      __hip_atomic_store(&part[(b * NVQ + s) * 8 + slice], pack,
                         __ATOMIC_RELAXED, __HIP_MEMORY_SCOPE_AGENT);
      __hip_atomic_fetch_add(&cnt[s], 1u, __ATOMIC_RELEASE, __HIP_MEMORY_SCOPE_AGENT);
      int guard = 0;   // RELAXED poll (no cache invalidation per iteration)
      while (__hip_atomic_load(&cnt[s], __ATOMIC_RELAXED, __HIP_MEMORY_SCOPE_AGENT) < 128u
             && guard < (1 << 22)) { __builtin_amdgcn_s_sleep(8); ++guard; }
      (void)__hip_atomic_load(&cnt[s], __ATOMIC_ACQUIRE, __HIP_MEMORY_SCOPE_AGENT);
      unsigned long long best =
          __hip_atomic_load(&part[(b * NVQ + s) * 8 + 0], __ATOMIC_RELAXED, __HIP_MEMORY_SCOPE_AGENT);
      #pragma unroll
      for (int s2 = 1; s2 < 8; ++s2) {
        unsigned long long v =
            __hip_atomic_load(&part[(b * NVQ + s) * 8 + s2], __ATOMIC_RELAXED, __HIP_MEMORY_SCOPE_AGENT);
        if (v < best) best = v;   // u64 min == lexicographic (dist, first idx)
      }
      bcast = (int)(best & 0xffffffffULL);
    }
    __syncthreads();
    if (s < NVQ - 1) r_s[t] -= emb[((size_t)s * NCODES + bcast) * LDIM + t];
    __syncthreads();
  }

  // ---- post-barrier film/loss duty ----
  if (vqb < 64) {        // film for (fb, li)
    const int fb = vqb >> 2;
    const int li = vqb & 3;
    const int l  = li + 1;
    int w[NVQ];
    #pragma unroll
    for (int s = 0; s < NVQ; ++s) {
      unsigned long long best =
          __hip_atomic_load(&part[(fb * NVQ + s) * 8 + 0], __ATOMIC_RELAXED, __HIP_MEMORY_SCOPE_AGENT);
      #pragma unroll
      for (int s2 = 1; s2 < 8; ++s2) {
        unsigned long long v =
            __hip_atomic_load(&part[(fb * NVQ + s) * 8 + s2], __ATOMIC_RELAXED, __HIP_MEMORY_SCOPE_AGENT);
        if (v < best) best = v;
      }
      w[s] = (int)(best & 0xffffffffULL);
    }
    float z = 0.f;
    #pragma unroll
    for (int s = 0; s < NVQ; ++s)
      z += emb[((size_t)s * NCODES + w[s]) * LDIM + t];   // effective_z
    __syncthreads();
    r_s[t] = z;          // reuse as z_s
    __syncthreads();
    float m1 = mod_b[l * 2 * HID + t];
    float m2 = mod_b[l * 2 * HID + HID + t];
    const float* Wm = mod_W + (size_t)l * LDIM * 2 * HID;
    #pragma unroll 4
    for (int d = 0; d < LDIM; ++d) {
      float zd = r_s[d];
      m1 = fmaf(zd, Wm[d * 2 * HID + t], m1);
      m2 = fmaf(zd, Wm[d * 2 * HID + HID + t], m2);
    }
    float* film = ws + FILM_OFF;
    film[((fb * 4 + li) * 2 + 0) * HID + t] = 1.f + m1;
    film[((fb * 4 + li) * 2 + 1) * HID + t] = m2;
  } else if (vqb == 64) {   // loss
    float acc = 0.f;
    for (int bb = 0; bb < BATCH; ++bb) {
      int w[NVQ];
      #pragma unroll
      for (int s = 0; s < NVQ; ++s) {
        unsigned long long best =
            __hip_atomic_load(&part[(bb * NVQ + s) * 8 + 0], __ATOMIC_RELAXED, __HIP_MEMORY_SCOPE_AGENT);
        #pragma unroll
        for (int s2 = 1; s2 < 8; ++s2) {
          unsigned long long v =
              __hip_atomic_load(&part[(bb * NVQ + s) * 8 + s2], __ATOMIC_RELAXED, __HIP_MEMORY_SCOPE_AGENT);
          if (v < best) best = v;
        }
        w[s] = (int)(best & 0xffffffffULL);
      }
      const int ibb = lidx[bb];
      float r = 0.f;
      #pragma unroll
      for (int v = 0; v < NVQ; ++v) r += latents[((size_t)ibb * NVQ + v) * LDIM + t];
      #pragma unroll
      for (int s = 0; s < NVQ; ++s) {
        float e = emb[((size_t)s * NCODES + w[s]) * LDIM + t];
        float d = e - r;
        acc += d * d;
        r -= e;
      }
    }
    __syncthreads();
    mval[t] = acc;
    __syncthreads();
    for (int off = 128; off > 0; off >>= 1) {
      if (t < off) mval[t] += mval[t + off];
      __syncthreads();
    }
    if (t == 0) loss_out[0] = mval[0] * (CC_ / (NVQ * BATCH * LDIM));
  }

  // ---- replay-safe teardown: last of 128 VQ blocks resets barrier state ----
  __syncthreads();
  if (t == 0) {
    unsigned int prev =
        __hip_atomic_fetch_add(done, 1u, __ATOMIC_ACQ_REL, __HIP_MEMORY_SCOPE_AGENT);
    if (prev == 127u) {
      #pragma unroll
      for (int i = 0; i < 8; ++i)
        __hip_atomic_store(&cnt[i], 0u, __ATOMIC_RELAXED, __HIP_MEMORY_SCOPE_AGENT);
      __hip_atomic_store(done, 0u, __ATOMIC_RELAXED, __HIP_MEMORY_SCOPE_AGENT);
      __hip_atomic_store(flag, 0u, __ATOMIC_RELEASE, __HIP_MEMORY_SCOPE_AGENT);
    }
  }
}

// ---------------- FAST siren: PTILE=64, 2 blocks/CU (r12-r15 proven, unchanged) ----------------
__global__ __launch_bounds__(512) void siren_mfma_fast(
    const float* __restrict__ coords,
    const float* __restrict__ W0,
    const float* __restrict__ b0,
    const float* __restrict__ bhv,
    const float* __restrict__ Wl,
    const float* __restrict__ bl,
    const float* __restrict__ ws,
    float* __restrict__ out) {
  __shared__ short x_h[PTILE * 264];
  __shared__ short x_l[PTILE * 264];
  __shared__ float osum[PTILE * 8 * 3];
  const int tid = threadIdx.x;
  const int bp = blockIdx.x;
  const int b = bp >> 6;
  const int tile = bp & 63;
  const int pbase = b * NPTS + tile * PTILE;

  {
    const int oct = tid >> 6;
    const int p = tid & 63;
    const float c0 = coords[(size_t)(pbase + p) * 2 + 0];
    const float c1 = coords[(size_t)(pbase + p) * 2 + 1];
    const int d0 = oct * 32;
    for (int i = 0; i < 32; i += 8) {
      short8 hv, lv;
      #pragma unroll
      for (int j = 0; j < 8; ++j) {
        int d = d0 + i + j;
        float pre = fmaf(c0, W0[d], fmaf(c1, W0[HID + d], b0[d]));
        short hi, lo;
        split_trunc(__sinf(OMEGA_ * pre), hi, lo);
        hv[j] = hi; lv[j] = lo;
      }
      *(short8*)&x_h[p * 264 + d0 + i] = hv;
      *(short8*)&x_l[p * 264 + d0 + i] = lv;
    }
  }

  const int lane = tid & 63;
  const int hq = tid >> 6;
  const int hb = hq * 32;
  const int n = lane & 15;
  const int q = lane >> 4;

  const short* wp_hi = (const short*)((const char*)ws + WP_BYTE);
  const short* wp_lo = wp_hi + PLANE_SHORTS;
  const float* film = ws + FILM_OFF;

  for (int layer = 1; layer < NLAY; ++layer) {
    const int li = layer - 1;
    f32x4 acc[4][2];
    #pragma unroll
    for (int pt = 0; pt < 4; ++pt)
      #pragma unroll
      for (int ht = 0; ht < 2; ++ht)
        acc[pt][ht] = (f32x4){0.f, 0.f, 0.f, 0.f};

    __syncthreads();

    #pragma unroll 2
    for (int kc = 0; kc < HID; kc += 32) {
      const int c = kc >> 5;
      short8 Bh[2], Bl[2];
      #pragma unroll
      for (int ht = 0; ht < 2; ++ht) {
        const size_t wb = ((((size_t)li * 16 + hq * 2 + ht) * 8 + c) * 64 + lane) * 8;
        Bh[ht] = *(const short8*)&wp_hi[wb];
        Bl[ht] = *(const short8*)&wp_lo[wb];
      }
      short8 Ah[4], Al[4];
      #pragma unroll
      for (int pt = 0; pt < 4; ++pt) {
        const int xb = (pt * 16 + n) * 264 + kc + q * 8;
        Ah[pt] = *(const short8*)&x_h[xb];
        Al[pt] = *(const short8*)&x_l[xb];
      }
      #pragma unroll
      for (int ht = 0; ht < 2; ++ht)
        #pragma unroll
        for (int pt = 0; pt < 4; ++pt)
          acc[pt][ht] = __builtin_amdgcn_mfma_f32_16x16x32_bf16(Ah[pt], Bh[ht], acc[pt][ht], 0, 0, 0);
      #pragma unroll
      for (int ht = 0; ht < 2; ++ht)
        #pragma unroll
        for (int pt = 0; pt < 4; ++pt)
          acc[pt][ht] = __builtin_amdgcn_mfma_f32_16x16x32_bf16(Ah[pt], Bl[ht], acc[pt][ht], 0, 0, 0);
      #pragma unroll
      for (int ht = 0; ht < 2; ++ht)
        #pragma unroll
        for (int pt = 0; pt < 4; ++pt)
          acc[pt][ht] = __builtin_amdgcn_mfma_f32_16x16x32_bf16(Al[pt], Bh[ht], acc[pt][ht], 0, 0, 0);
    }

    __syncthreads();

    #pragma unroll
    for (int ht = 0; ht < 2; ++ht) {
      const int h = hb + ht * 16 + n;
      const float bias = bhv[li * HID + h];
      const float g1 = film[((b * 4 + li) * 2 + 0) * HID + h];
      const float bt = film[((b * 4 + li) * 2 + 1) * HID + h];
      #pragma unroll
      for (int pt = 0; pt < 4; ++pt) {
        #pragma unroll
        for (int r = 0; r < 4; ++r) {
          float pre = acc[pt][ht][r] + bias;
          pre = fmaf(pre, g1, bt);
          short hi, lo;
          split_trunc(__sinf(OMEGA_ * pre), hi, lo);
          const int row = pt * 16 + q * 4 + r;
          x_h[row * 264 + h] = hi;
          x_l[row * 264 + h] = lo;
        }
      }
    }
  }
  __syncthreads();

  {
    const int p = tid >> 3;
    const int dq = tid & 7;
    float v0 = 0.f, v1 = 0.f, v2 = 0.f;
    for (int i = 0; i < 32; ++i) {
      int d = dq * 32 + i;
      float xv = bf16_hi_f((unsigned short)x_h[p * 264 + d]) +
                 bf16_hi_f((unsigned short)x_l[p * 264 + d]);
      v0 = fmaf(xv, Wl[d * 3 + 0], v0);
      v1 = fmaf(xv, Wl[d * 3 + 1], v1);
      v2 = fmaf(xv, Wl[d * 3 + 2], v2);
    }
    osum[(p * 8 + dq) * 3 + 0] = v0;
    osum[(p * 8 + dq) * 3 + 1] = v1;
    osum[(p * 8 + dq) * 3 + 2] = v2;
  }
  __syncthreads();
  if (tid < PTILE) {
    const int p = tid;
    float v[3] = {bl[0], bl[1], bl[2]};
    #pragma unroll
    for (int dq = 0; dq < 8; ++dq)
      #pragma unroll
      for (int c = 0; c < 3; ++c) v[c] += osum[(p * 8 + dq) * 3 + c];
    size_t o = (size_t)(pbase + p) * 3;
    out[o + 0] = v[0]; out[o + 1] = v[1]; out[o + 2] = v[2];
  }
}

// ---------------- FALLBACK siren (round-8-proven; dead when ws large) ----------------
__global__ __launch_bounds__(512) void siren_mfma(
    const float* __restrict__ coords,
    const float* __restrict__ W0,
    const float* __restrict__ b0,
    const float* __restrict__ Whg,
    const float* __restrict__ bhv,
    const float* __restrict__ Wl,
    const float* __restrict__ bl,
    const float* __restrict__ ws,
    float* __restrict__ out) {
  __shared__ unsigned int x_u[128 * 260];
  __shared__ float osum[128 * 4 * 3];
  const int tid = threadIdx.x;
  const int bp = blockIdx.x;
  const int b = bp >> 5;
  const int tile = bp & 31;
  const int pbase = b * NPTS + tile * 128;
  {
    const int quarter = tid >> 7;
    const int p = tid & 127;
    const float c0 = coords[(size_t)(pbase + p) * 2 + 0];
    const float c1 = coords[(size_t)(pbase + p) * 2 + 1];
    const int d0 = quarter * 64;
    for (int i = 0; i < 64; i += 4) {
      unsigned int buf[4];
      #pragma unroll
      for (int j = 0; j < 4; ++j) {
        int d = d0 + i + j;
        float pre = fmaf(c0, W0[d], fmaf(c1, W0[HID + d], b0[d]));
        buf[j] = pack_split(__sinf(OMEGA_ * pre));
      }
      *(uint4*)&x_u[p * 260 + d0 + i] = *(uint4*)buf;
    }
  }
  const int lane = tid & 63;
  const int wv = tid >> 6;
  const int pg = wv & 1;
  const int hq = wv >> 1;
  const int pb = pg * 64;
  const int hb = hq * 64;
  const int n = lane & 15;
  const int q = lane >> 4;
  const float* film = ws + FILM_OFF;
  for (int layer = 1; layer < NLAY; ++layer) {
    const int li = layer - 1;
    f32x4 acc[4][4];
    #pragma unroll
    for (int pt = 0; pt < 4; ++pt)
      #pragma unroll
      for (int ht = 0; ht < 4; ++ht)
        acc[pt][ht] = (f32x4){0.f, 0.f, 0.f, 0.f};
    __syncthreads();
    for (int kc = 0; kc < HID; kc += 32) {
      short8 Bh[4], Bl[4];
      #pragma unroll
      for (int ht = 0; ht < 4; ++ht) {
        const float* wbase = Whg + ((size_t)(li * 256 + kc + q * 8)) * 256 + hb + ht * 16 + n;
        #pragma unroll
        for (int j = 0; j < 8; ++j) {
          short hi, lo;
          split_trunc(wbase[(size_t)j * 256], hi, lo);
          Bh[ht][j] = hi; Bl[ht][j] = lo;
        }
      }
      short8 ah[4], al[4];
      #pragma unroll
      for (int pt = 0; pt < 4; ++pt) {
        const uint4* ap = (const uint4*)&x_u[(pb + pt * 16 + n) * 260 + kc + q * 8];
        uint4 a0 = ap[0], a1 = ap[1];
        unsigned int aw[8] = {a0.x, a0.y, a0.z, a0.w, a1.x, a1.y, a1.z, a1.w};
        #pragma unroll
        for (int j = 0; j < 8; ++j) {
          ah[pt][j] = (short)(aw[j] >> 16);
          al[pt][j] = (short)(aw[j] & 0xffffu);
        }
      }
      #pragma unroll
      for (int ht = 0; ht < 4; ++ht)
        #pragma unroll
        for (int pt = 0; pt < 4; ++pt)
          acc[pt][ht] = __builtin_amdgcn_mfma_f32_16x16x32_bf16(ah[pt], Bh[ht], acc[pt][ht], 0, 0, 0);
      #pragma unroll
      for (int ht = 0; ht < 4; ++ht)
        #pragma unroll
        for (int pt = 0; pt < 4; ++pt)
          acc[pt][ht] = __builtin_amdgcn_mfma_f32_16x16x32_bf16(ah[pt], Bl[ht], acc[pt][ht], 0, 0, 0);
      #pragma unroll
      for (int ht = 0; ht < 4; ++ht)
        #pragma unroll
        for (int pt = 0; pt < 4; ++pt)
          acc[pt][ht] = __builtin_amdgcn_mfma_f32_16x16x32_bf16(al[pt], Bh[ht], acc[pt][ht], 0, 0, 0);
    }
    __syncthreads();
    #pragma unroll
    for (int ht = 0; ht < 4; ++ht) {
      const int h = hb + ht * 16 + n;
      const float bias = bhv[li * HID + h];
      const float g1 = film[((b * 4 + li) * 2 + 0) * HID + h];
      const float bt = film[((b * 4 + li) * 2 + 1) * HID + h];
      #pragma unroll
      for (int pt = 0; pt < 4; ++pt) {
        #pragma unroll
        for (int r = 0; r < 4; ++r) {
          float pre = acc[pt][ht][r] + bias;
          pre = fmaf(pre, g1, bt);
          x_u[(pb + pt * 16 + q * 4 + r) * 260 + h] = pack_split(__sinf(OMEGA_ * pre));
        }
      }
    }
  }
  __syncthreads();
  {
    const int p = tid >> 2;
    const int dq = tid & 3;
    float v0 = 0.f, v1 = 0.f, v2 = 0.f;
    for (int i = 0; i < 64; ++i) {
      int d = dq * 64 + i;
      unsigned int wrd = x_u[p * 260 + d];
      float xv = bf16_hi_f((unsigned short)(wrd >> 16)) +
                 bf16_hi_f((unsigned short)(wrd & 0xffffu));
      v0 = fmaf(xv, Wl[d * 3 + 0], v0);
      v1 = fmaf(xv, Wl[d * 3 + 1], v1);
      v2 = fmaf(xv, Wl[d * 3 + 2], v2);
    }
    osum[(p * 4 + dq) * 3 + 0] = v0;
    osum[(p * 4 + dq) * 3 + 1] = v1;
    osum[(p * 4 + dq) * 3 + 2] = v2;
  }
  __syncthreads();
  if (tid < 128) {
    const int p = tid;
    float v[3] = {bl[0], bl[1], bl[2]};
    #pragma unroll
    for (int dq = 0; dq < 4; ++dq)
      #pragma unroll
      for (int c = 0; c < 3; ++c) v[c] += osum[(p * 4 + dq) * 3 + c];
    size_t o = (size_t)(pbase + p) * 3;
    out[o + 0] = v[0]; out[o + 1] = v[1]; out[o + 2] = v[2];
  }
}

extern "C" void kernel_launch(void* const* d_in, const int* in_sizes, int n_in,
                              void* d_out, int out_size, void* d_ws, size_t ws_size,
                              hipStream_t stream) {
  (void)in_sizes; (void)n_in;
  const float* coords  = (const float*)d_in[0];
  const int*   lidx    = (const int*)d_in[1];
  const float* latents = (const float*)d_in[2];
  const float* emb     = (const float*)d_in[3];
  const float* mod_W   = (const float*)d_in[4];
  const float* mod_b   = (const float*)d_in[5];
  const float* W0      = (const float*)d_in[6];
  const float* b0      = (const float*)d_in[7];
  const float* Wh      = (const float*)d_in[8];
  const float* bh      = (const float*)d_in[9];
  const float* Wl      = (const float*)d_in[10];
  const float* bl      = (const float*)d_in[11];
  float* out = (float*)d_out;
  float* ws  = (float*)d_ws;
  float* loss_out = out + (out_size - 1);

  const bool fast = (ws_size >= FAST_WS_NEEDED);
  fused_pre<<<160, 256, 0, stream>>>(lidx, latents, emb, Wh, mod_W, mod_b, ws,
                                     loss_out, fast ? 1 : 0);
  if (fast)
    siren_mfma_fast<<<(BATCH * NPTS) / PTILE, 512, 0, stream>>>(coords, W0, b0, bh, Wl, bl, ws, out);
  else
    siren_mfma<<<(BATCH * NPTS) / 128, 512, 0, stream>>>(coords, W0, b0, Wh, bh, Wl, bl, ws, out);
}